// Round 12
// baseline (128.953 us; speedup 1.0000x reference)
//
#include <hip/hip_runtime.h>
#include <hip/hip_bf16.h>
#include <math.h>

typedef __hip_bfloat16 bf16;
typedef __attribute__((ext_vector_type(8))) short bf16x8;   // MFMA A/B frag (8 bf16)
typedef __attribute__((ext_vector_type(4))) float f32x4;    // MFMA C/D frag

#define NROW 4096
#define DIM  1024
#define APP  256
#define WIN  640          // band window per 128-row j-tile: 128 + 2*APP
#define VTPW 4608         // padded Vt width: 256 | 4096 | 256

__device__ __forceinline__ unsigned short f2bu(float f) {
    bf16 h = __float2bfloat16(f);
    return *reinterpret_cast<unsigned short*>(&h);
}
__device__ __forceinline__ float bu2f(unsigned short u) {
    bf16 h; *reinterpret_cast<unsigned short*>(&h) = u;
    return __bfloat162float(h);
}
__device__ __forceinline__ unsigned pk2(float a, float b) {
    return (unsigned)f2bu(a) | ((unsigned)f2bu(b) << 16);
}
__device__ __forceinline__ void gload_lds16(const void* g, void* l) {
    __builtin_amdgcn_global_load_lds(
        (const __attribute__((address_space(1))) unsigned int*)g,
        (__attribute__((address_space(3))) unsigned int*)l, 16, 0, 0);
}

// ================= fused prep: cast x | cast/transpose 5 weights | zero Vtp pads =================
struct PrepArgs { const float* x; bf16* xb; const float* srcw[5]; bf16* dstw[5]; bf16* Vtp; };
__global__ __launch_bounds__(256) void prep_kernel(PrepArgs p) {
    __shared__ float T[64][65];
    const int bid = blockIdx.x, t = threadIdx.x;
    if (bid < 2048) {
        size_t base = ((size_t)bid * 256 + t) * 8;
        float4 v0 = *(const float4*)(p.x + base);
        float4 v1 = *(const float4*)(p.x + base + 4);
        uint4 o;
        o.x = pk2(v0.x, v0.y); o.y = pk2(v0.z, v0.w);
        o.z = pk2(v1.x, v1.y); o.w = pk2(v1.z, v1.w);
        *(uint4*)(p.xb + base) = o;
        return;
    }
    if (bid < 3328) {
        int r = bid - 2048;
        const int z = r >> 8; r &= 255;
        const int r0 = (r & 15) * 64, c0 = (r >> 4) * 64;
        const float* in = p.srcw[z];
        bf16* out = p.dstw[z];
        if (z < 3) {
            #pragma unroll
            for (int c = 0; c < 4; ++c) {
                int row = (t >> 4) + c * 16, col = (t & 15) * 4;
                float4 v = *(const float4*)(in + (size_t)(r0 + row) * 1024 + c0 + col);
                uint2 o; o.x = pk2(v.x, v.y); o.y = pk2(v.z, v.w);
                *(uint2*)(out + (size_t)(r0 + row) * 1024 + c0 + col) = o;
            }
            return;
        }
        #pragma unroll
        for (int c = 0; c < 4; ++c) {
            int row = (t >> 4) + c * 16, col = (t & 15) * 4;
            float4 v = *(const float4*)(in + (size_t)(r0 + row) * 1024 + c0 + col);
            T[row][col] = v.x; T[row][col + 1] = v.y; T[row][col + 2] = v.z; T[row][col + 3] = v.w;
        }
        __syncthreads();
        #pragma unroll
        for (int c = 0; c < 4; ++c) {
            int orow = (t >> 4) + c * 16, ocol = (t & 15) * 4;
            uint2 o;
            o.x = pk2(T[ocol][orow], T[ocol + 1][orow]);
            o.y = pk2(T[ocol + 2][orow], T[ocol + 3][orow]);
            *(uint2*)(out + (size_t)(c0 + orow) * 1024 + r0 + ocol) = o;
        }
        return;
    }
    {
        int idx = (bid - 3328) * 256 + t;
        int row = idx >> 7;
        int c4  = idx & 127;
        int col = (c4 < 64) ? (c4 * 4) : (4352 + (c4 - 64) * 4);
        *(uint2*)(p.Vtp + (size_t)row * VTPW + col) = (uint2){0u, 0u};
    }
}

// ================= bf16 MFMA GEMM: C[M,N] = act(alpha*A@Bt^T + bias) =================
// A row-major [M,K] stride lda; Bt row-major [N,K] stride ldb; C stride ldc.
// pv!=0: Bt base += (m0>>7)*128 (banded PV: per-128-j-tile column offset into Vtp).
template <int BM, int BN>
__global__ __launch_bounds__(256) void gemm_bt(
    const bf16* __restrict__ A, int lda, const bf16* __restrict__ Bt, int ldb,
    bf16* __restrict__ C, int ldc, int K,
    float alpha, const float* __restrict__ bias, int relu, int pv)
{
    constexpr int WM = BM / 2, WN = BN / 2, AI = WM / 16, BJ = WN / 16;
    __shared__ bf16 As[BM * 64];
    __shared__ bf16 Bs[BN * 64];
    const int t = threadIdx.x, l = t & 63, w = t >> 6;
    const int wr = w >> 1, wc = w & 1;
    const int jl = l & 15, g = l >> 4;
    const int m0 = blockIdx.y * BM, n0 = blockIdx.x * BN;
    const bf16* Btb = pv ? (Bt + (size_t)(m0 >> 7) * 128) : Bt;

    f32x4 acc[AI][BJ];
    #pragma unroll
    for (int i = 0; i < AI; ++i)
        #pragma unroll
        for (int j = 0; j < BJ; ++j) acc[i][j] = (f32x4){0.f, 0.f, 0.f, 0.f};

    for (int kk = 0; kk < K; kk += 64) {
        __syncthreads();
        #pragma unroll
        for (int c = 0; c < BM / 32; ++c) {
            int q = t + c * 256;
            int row = q >> 3;
            int kel = ((q & 7) ^ (row & 7)) << 3;
            gload_lds16(A + (size_t)(m0 + row) * lda + kk + kel,
                        (char*)As + (c * 256 + w * 64) * 16);
        }
        #pragma unroll
        for (int c = 0; c < BN / 32; ++c) {
            int q = t + c * 256;
            int row = q >> 3;
            int kel = ((q & 7) ^ (row & 7)) << 3;
            gload_lds16(Btb + (size_t)(n0 + row) * ldb + kk + kel,
                        (char*)Bs + (c * 256 + w * 64) * 16);
        }
        __syncthreads();
        #pragma unroll
        for (int ks = 0; ks < 2; ++ks) {
            bf16x8 af[AI], bfr[BJ];
            #pragma unroll
            for (int i = 0; i < AI; ++i) {
                int ra = wr * WM + i * 16 + jl;
                af[i] = *(const bf16x8*)((char*)As + ra * 128 + ((ks * 64 + g * 16) ^ ((ra & 7) << 4)));
            }
            #pragma unroll
            for (int j = 0; j < BJ; ++j) {
                int rb = wc * WN + j * 16 + jl;
                bfr[j] = *(const bf16x8*)((char*)Bs + rb * 128 + ((ks * 64 + g * 16) ^ ((rb & 7) << 4)));
            }
            #pragma unroll
            for (int i = 0; i < AI; ++i)
                #pragma unroll
                for (int j = 0; j < BJ; ++j)
                    acc[i][j] = __builtin_amdgcn_mfma_f32_16x16x32_bf16(af[i], bfr[j], acc[i][j], 0, 0, 0);
        }
    }

    const int g4 = g * 4;
    #pragma unroll
    for (int j = 0; j < BJ; ++j) {
        int col = n0 + wc * WN + j * 16 + jl;
        float bv = bias ? bias[col] : 0.f;
        #pragma unroll
        for (int i = 0; i < AI; ++i) {
            int rowb = m0 + wr * WM + i * 16 + g4;
            #pragma unroll
            for (int r = 0; r < 4; ++r) {
                float vv = alpha * acc[i][j][r] + bv;
                if (relu) vv = fmaxf(vv, 0.f);
                C[(size_t)(rowb + r) * ldc + col] = __float2bfloat16(vv);
            }
        }
    }
}

// ================= combined QV GEMM with split epilogue =================
// O = xb @ Wcat^T, Wcat = [WqkT; wvoT] (2048 rows). Columns 0..1023 -> Qh normally;
// columns 1024..2047 -> written TRANSPOSED into Vtp[d][256+j] (V'^T, padded).
__global__ __launch_bounds__(256) void gemm_kqv(
    const bf16* __restrict__ xb, const bf16* __restrict__ Wcat,
    bf16* __restrict__ Qh, bf16* __restrict__ Vtp)
{
    constexpr int BM = 128, BN = 128, WM = 64, WN = 64, AI = 4, BJ = 4;
    __shared__ bf16 As[BM * 64];
    __shared__ bf16 Bs[BN * 64];
    const int t = threadIdx.x, l = t & 63, w = t >> 6;
    const int wr = w >> 1, wc = w & 1;
    const int jl = l & 15, g = l >> 4;
    const int m0 = blockIdx.y * BM, n0 = blockIdx.x * BN;

    f32x4 acc[AI][BJ];
    #pragma unroll
    for (int i = 0; i < AI; ++i)
        #pragma unroll
        for (int j = 0; j < BJ; ++j) acc[i][j] = (f32x4){0.f, 0.f, 0.f, 0.f};

    for (int kk = 0; kk < DIM; kk += 64) {
        __syncthreads();
        #pragma unroll
        for (int c = 0; c < 4; ++c) {
            int q = t + c * 256;
            int row = q >> 3;
            int kel = ((q & 7) ^ (row & 7)) << 3;
            gload_lds16(xb + (size_t)(m0 + row) * DIM + kk + kel,
                        (char*)As + (c * 256 + w * 64) * 16);
            gload_lds16(Wcat + (size_t)(n0 + row) * DIM + kk + kel,
                        (char*)Bs + (c * 256 + w * 64) * 16);
        }
        __syncthreads();
        #pragma unroll
        for (int ks = 0; ks < 2; ++ks) {
            bf16x8 af[AI], bfr[BJ];
            #pragma unroll
            for (int i = 0; i < AI; ++i) {
                int ra = wr * WM + i * 16 + jl;
                af[i] = *(const bf16x8*)((char*)As + ra * 128 + ((ks * 64 + g * 16) ^ ((ra & 7) << 4)));
            }
            #pragma unroll
            for (int j = 0; j < BJ; ++j) {
                int rb = wc * WN + j * 16 + jl;
                bfr[j] = *(const bf16x8*)((char*)Bs + rb * 128 + ((ks * 64 + g * 16) ^ ((rb & 7) << 4)));
            }
            #pragma unroll
            for (int i = 0; i < AI; ++i)
                #pragma unroll
                for (int j = 0; j < BJ; ++j)
                    acc[i][j] = __builtin_amdgcn_mfma_f32_16x16x32_bf16(af[i], bfr[j], acc[i][j], 0, 0, 0);
        }
    }

    const int g4 = g * 4;
    if (n0 < 1024) {
        // Qh half: standard row-major store
        #pragma unroll
        for (int j = 0; j < BJ; ++j) {
            int col = n0 + wc * WN + j * 16 + jl;
            #pragma unroll
            for (int i = 0; i < AI; ++i) {
                int rowb = m0 + wr * WM + i * 16 + g4;
                #pragma unroll
                for (int r = 0; r < 4; ++r)
                    Qh[(size_t)(rowb + r) * DIM + col] = __float2bfloat16(acc[i][j][r]);
            }
        }
    } else {
        // V' half: acc[i][j][r] = V'[rowb+r][d], d = col-1024 -> Vtp[d][256+rowb+r]
        // r=0..3 are consecutive j -> one contiguous 8B store.
        #pragma unroll
        for (int j = 0; j < BJ; ++j) {
            int d = n0 - 1024 + wc * WN + j * 16 + jl;
            #pragma unroll
            for (int i = 0; i < AI; ++i) {
                int rowb = m0 + wr * WM + i * 16 + g4;
                uint2 o;
                o.x = pk2(acc[i][j][0], acc[i][j][1]);
                o.y = pk2(acc[i][j][2], acc[i][j][3]);
                *(uint2*)(Vtp + (size_t)d * VTPW + 256 + rowb) = o;
            }
        }
    }
}

// ================= two 1024^3 mini GEMMs, 128x64 tiles (z=0: WqkT=wk@wq^T, z=1: wvoT=wo^T@wv^T) =================
struct MiniPtrs { const bf16* A[2]; const bf16* Bt[2]; bf16* C[2]; };
__global__ __launch_bounds__(256) void gemm_mini(MiniPtrs p) {
    constexpr int BM = 128, BN = 64, WM = 64, WN = 32, AI = 4, BJ = 2;
    __shared__ bf16 As[BM * 64];
    __shared__ bf16 Bs[BN * 64];
    const bf16* A  = p.A[blockIdx.z];
    const bf16* Bt = p.Bt[blockIdx.z];
    bf16* C        = p.C[blockIdx.z];
    const int t = threadIdx.x, l = t & 63, w = t >> 6;
    const int wr = w >> 1, wc = w & 1;
    const int jl = l & 15, g = l >> 4;
    const int m0 = blockIdx.y * BM, n0 = blockIdx.x * BN;

    f32x4 acc[AI][BJ];
    #pragma unroll
    for (int i = 0; i < AI; ++i)
        #pragma unroll
        for (int j = 0; j < BJ; ++j) acc[i][j] = (f32x4){0.f, 0.f, 0.f, 0.f};

    for (int kk = 0; kk < DIM; kk += 64) {
        __syncthreads();
        #pragma unroll
        for (int c = 0; c < BM / 32; ++c) {
            int q = t + c * 256;
            int row = q >> 3;
            int kel = ((q & 7) ^ (row & 7)) << 3;
            gload_lds16(A + (size_t)(m0 + row) * DIM + kk + kel,
                        (char*)As + (c * 256 + w * 64) * 16);
        }
        #pragma unroll
        for (int c = 0; c < BN / 32; ++c) {
            int q = t + c * 256;
            int row = q >> 3;
            int kel = ((q & 7) ^ (row & 7)) << 3;
            gload_lds16(Bt + (size_t)(n0 + row) * DIM + kk + kel,
                        (char*)Bs + (c * 256 + w * 64) * 16);
        }
        __syncthreads();
        #pragma unroll
        for (int ks = 0; ks < 2; ++ks) {
            bf16x8 af[AI], bfr[BJ];
            #pragma unroll
            for (int i = 0; i < AI; ++i) {
                int ra = wr * WM + i * 16 + jl;
                af[i] = *(const bf16x8*)((char*)As + ra * 128 + ((ks * 64 + g * 16) ^ ((ra & 7) << 4)));
            }
            #pragma unroll
            for (int j = 0; j < BJ; ++j) {
                int rb = wc * WN + j * 16 + jl;
                bfr[j] = *(const bf16x8*)((char*)Bs + rb * 128 + ((ks * 64 + g * 16) ^ ((rb & 7) << 4)));
            }
            #pragma unroll
            for (int i = 0; i < AI; ++i)
                #pragma unroll
                for (int j = 0; j < BJ; ++j)
                    acc[i][j] = __builtin_amdgcn_mfma_f32_16x16x32_bf16(af[i], bfr[j], acc[i][j], 0, 0, 0);
        }
    }

    const int g4 = g * 4;
    #pragma unroll
    for (int j = 0; j < BJ; ++j) {
        int col = n0 + wc * WN + j * 16 + jl;
        #pragma unroll
        for (int i = 0; i < AI; ++i) {
            int rowb = m0 + wr * WM + i * 16 + g4;
            #pragma unroll
            for (int r = 0; r < 4; ++r)
                C[(size_t)(rowb + r) * DIM + col] = __float2bfloat16(acc[i][j][r]);
        }
    }
}

// ================= banded score GEMM: St[j][iw] = 0.06 * Qh[win0+iw] . x[j] =================
__global__ __launch_bounds__(256) void score_gemm(const bf16* __restrict__ Qh,
                                                  const bf16* __restrict__ xb,
                                                  bf16* __restrict__ St)
{
    constexpr int WM = 32, WN = 64, AI = 2, BJ = 4;
    __shared__ bf16 As[64 * 64];
    __shared__ bf16 Bs[128 * 64];
    const int t = threadIdx.x, l = t & 63, w = t >> 6;
    const int wr = w >> 1, wc = w & 1;
    const int jl = l & 15, g = l >> 4;
    const int tt = blockIdx.y;              // j-tile 0..31
    const int c0 = blockIdx.x * 64;         // iw chunk base
    const int win0 = tt * 128 - APP;        // window start
    const bf16* Kb = xb + (size_t)tt * 128 * DIM;

    f32x4 acc[AI][BJ];
    #pragma unroll
    for (int i = 0; i < AI; ++i)
        #pragma unroll
        for (int j = 0; j < BJ; ++j) acc[i][j] = (f32x4){0.f, 0.f, 0.f, 0.f};

    for (int kk = 0; kk < DIM; kk += 64) {
        __syncthreads();
        #pragma unroll
        for (int c = 0; c < 2; ++c) {
            int q = t + c * 256;
            int row = q >> 3;
            int kel = ((q & 7) ^ (row & 7)) << 3;
            int rg = win0 + c0 + row;
            rg = min(max(rg, 0), NROW - 1);
            gload_lds16(Qh + (size_t)rg * DIM + kk + kel,
                        (char*)As + (c * 256 + w * 64) * 16);
        }
        #pragma unroll
        for (int c = 0; c < 4; ++c) {
            int q = t + c * 256;
            int row = q >> 3;
            int kel = ((q & 7) ^ (row & 7)) << 3;
            gload_lds16(Kb + (size_t)row * DIM + kk + kel,
                        (char*)Bs + (c * 256 + w * 64) * 16);
        }
        __syncthreads();
        #pragma unroll
        for (int ks = 0; ks < 2; ++ks) {
            bf16x8 af[AI], bfr[BJ];
            #pragma unroll
            for (int i = 0; i < AI; ++i) {
                int ra = wr * WM + i * 16 + jl;
                af[i] = *(const bf16x8*)((char*)As + ra * 128 + ((ks * 64 + g * 16) ^ ((ra & 7) << 4)));
            }
            #pragma unroll
            for (int j = 0; j < BJ; ++j) {
                int rb = wc * WN + j * 16 + jl;
                bfr[j] = *(const bf16x8*)((char*)Bs + rb * 128 + ((ks * 64 + g * 16) ^ ((rb & 7) << 4)));
            }
            #pragma unroll
            for (int i = 0; i < AI; ++i)
                #pragma unroll
                for (int j = 0; j < BJ; ++j)
                    acc[i][j] = __builtin_amdgcn_mfma_f32_16x16x32_bf16(af[i], bfr[j], acc[i][j], 0, 0, 0);
        }
    }

    const int g4 = g * 4;
    #pragma unroll
    for (int j = 0; j < BJ; ++j) {
        int coll = wc * WN + j * 16 + jl;
        bf16* strow = St + (size_t)(tt * 128 + coll) * WIN;
        #pragma unroll
        for (int i = 0; i < AI; ++i) {
            int iwb = c0 + wr * WM + i * 16 + g4;
            #pragma unroll
            for (int r = 0; r < 4; ++r)
                strow[iwb + r] = __float2bfloat16(0.06f * acc[i][j][r]);
        }
    }
}

// ================= masked row softmax over the 640-wide band window =================
__global__ __launch_bounds__(256) void softmax_band(bf16* __restrict__ St)
{
    const int w = threadIdx.x >> 6, l = threadIdx.x & 63;
    const int j = blockIdx.x * 4 + w;
    const int tt = j >> 7, jt = j & 127;
    unsigned* row = (unsigned*)(St + (size_t)j * WIN);
    const int lo = max(jt, 256 - 128 * tt);
    const int hi = min(jt + 512, 4351 - 128 * tt);
    unsigned u[5]; float v[10];
    #pragma unroll
    for (int c = 0; c < 5; ++c) u[c] = row[l + 64 * c];
    float m = -3e38f;
    #pragma unroll
    for (int c = 0; c < 5; ++c) {
        int iw = 2 * (l + 64 * c);
        v[2 * c]     = (iw >= lo && iw <= hi)         ? bu2f((unsigned short)(u[c] & 0xffff)) : -3e38f;
        v[2 * c + 1] = (iw + 1 >= lo && iw + 1 <= hi) ? bu2f((unsigned short)(u[c] >> 16))    : -3e38f;
        m = fmaxf(m, fmaxf(v[2 * c], v[2 * c + 1]));
    }
    #pragma unroll
    for (int off = 32; off > 0; off >>= 1) m = fmaxf(m, __shfl_xor(m, off));
    float s = 0.f;
    #pragma unroll
    for (int c = 0; c < 10; ++c) {
        float e = (v[c] > -1e37f) ? __expf(v[c] - m) : 0.f;
        v[c] = e; s += e;
    }
    #pragma unroll
    for (int off = 32; off > 0; off >>= 1) s += __shfl_xor(s, off);
    const float inv = 1.f / s;
    #pragma unroll
    for (int c = 0; c < 5; ++c)
        row[l + 64 * c] = pk2(v[2 * c] * inv, v[2 * c + 1] * inv);
}

// ================= LayerNorm: O = LN(T + Xb) * g + b  (Xb bf16 residual, may be null) =================
__global__ __launch_bounds__(256) void ln_kernel(
    const bf16* __restrict__ T, const bf16* __restrict__ Xb,
    const float* __restrict__ g, const float* __restrict__ b, bf16* __restrict__ O)
{
    __shared__ float red1[4], red2[4];
    const int r = blockIdx.x, t = threadIdx.x, lane = t & 63, w = t >> 6;
    ushort4 tv = ((const ushort4*)(T + (size_t)r * DIM))[t];
    float v0 = bu2f(tv.x), v1 = bu2f(tv.y), v2 = bu2f(tv.z), v3 = bu2f(tv.w);
    if (Xb) {
        ushort4 xv = ((const ushort4*)(Xb + (size_t)r * DIM))[t];
        v0 += bu2f(xv.x); v1 += bu2f(xv.y); v2 += bu2f(xv.z); v3 += bu2f(xv.w);
    }
    float s = v0 + v1 + v2 + v3;
    #pragma unroll
    for (int off = 32; off > 0; off >>= 1) s += __shfl_xor(s, off);
    if (lane == 0) red1[w] = s;
    __syncthreads();
    float mu = (red1[0] + red1[1] + red1[2] + red1[3]) * (1.f / DIM);
    float d0 = v0 - mu, d1 = v1 - mu, d2 = v2 - mu, d3 = v3 - mu;
    float s2 = d0 * d0 + d1 * d1 + d2 * d2 + d3 * d3;
    #pragma unroll
    for (int off = 32; off > 0; off >>= 1) s2 += __shfl_xor(s2, off);
    if (lane == 0) red2[w] = s2;
    __syncthreads();
    float var = (red2[0] + red2[1] + red2[2] + red2[3]) * (1.f / DIM);
    float rstd = rsqrtf(var + 1e-3f);
    float4 gv = ((const float4*)g)[t];
    float4 bv = ((const float4*)b)[t];
    uint2 o;
    o.x = pk2(d0 * rstd * gv.x + bv.x, d1 * rstd * gv.y + bv.y);
    o.y = pk2(d2 * rstd * gv.z + bv.z, d3 * rstd * gv.w + bv.w);
    ((uint2*)(O + (size_t)r * DIM))[t] = o;
}

// ================= fused LN2 + final: out[r] = sigmoid(LN(T[r]).wkd + bkd) =================
__global__ __launch_bounds__(256) void lnfinal_kernel(
    const bf16* __restrict__ T, const float* __restrict__ g, const float* __restrict__ b,
    const float* __restrict__ wkd, const float* __restrict__ bkd, float* __restrict__ out)
{
    __shared__ float red1[4], red2[4], red3[4];
    const int r = blockIdx.x, t = threadIdx.x, lane = t & 63, w = t >> 6;
    ushort4 tv = ((const ushort4*)(T + (size_t)r * DIM))[t];
    float v0 = bu2f(tv.x), v1 = bu2f(tv.y), v2 = bu2f(tv.z), v3 = bu2f(tv.w);
    float s = v0 + v1 + v2 + v3;
    #pragma unroll
    for (int off = 32; off > 0; off >>= 1) s += __shfl_xor(s, off);
    if (lane == 0) red1[w] = s;
    __syncthreads();
    float mu = (red1[0] + red1[1] + red1[2] + red1[3]) * (1.f / DIM);
    float d0 = v0 - mu, d1 = v1 - mu, d2 = v2 - mu, d3 = v3 - mu;
    float s2 = d0 * d0 + d1 * d1 + d2 * d2 + d3 * d3;
    #pragma unroll
    for (int off = 32; off > 0; off >>= 1) s2 += __shfl_xor(s2, off);
    if (lane == 0) red2[w] = s2;
    __syncthreads();
    float var = (red2[0] + red2[1] + red2[2] + red2[3]) * (1.f / DIM);
    float rstd = rsqrtf(var + 1e-3f);
    float4 gv = ((const float4*)g)[t];
    float4 bv = ((const float4*)b)[t];
    float4 wv = ((const float4*)wkd)[t];
    float s3 = (d0 * rstd * gv.x + bv.x) * wv.x + (d1 * rstd * gv.y + bv.y) * wv.y
             + (d2 * rstd * gv.z + bv.z) * wv.z + (d3 * rstd * gv.w + bv.w) * wv.w;
    #pragma unroll
    for (int off = 32; off > 0; off >>= 1) s3 += __shfl_xor(s3, off);
    if (lane == 0) red3[w] = s3;
    __syncthreads();
    if (t == 0) {
        float tot = red3[0] + red3[1] + red3[2] + red3[3];
        out[r] = 1.f / (1.f + __expf(-(tot + bkd[0])));
    }
}

extern "C" void kernel_launch(void* const* d_in, const int* in_sizes, int n_in,
                              void* d_out, int out_size, void* d_ws, size_t ws_size,
                              hipStream_t stream) {
    const float* x    = (const float*)d_in[0];
    const float* wk   = (const float*)d_in[1];
    const float* wq   = (const float*)d_in[2];
    const float* wv   = (const float*)d_in[3];
    const float* wo   = (const float*)d_in[4];
    const float* wka  = (const float*)d_in[5];
    const float* bka  = (const float*)d_in[6];
    const float* wkd  = (const float*)d_in[7];
    const float* bkd  = (const float*)d_in[8];
    const float* g_y  = (const float*)d_in[9];
    const float* b_y  = (const float*)d_in[10];
    const float* g_ka = (const float*)d_in[11];
    const float* b_ka = (const float*)d_in[12];
    float* out = (float*)d_out;

    char* ws = (char*)d_ws;
    const size_t MB = 1u << 20;
    bf16* wkB  = (bf16*)(ws);              // 2 MB  wk (plain)
    bf16* wqB  = (bf16*)(ws + 2 * MB);     // 2 MB  wq (plain)
    bf16* wvB  = (bf16*)(ws + 4 * MB);     // 2 MB  wv (plain)
    bf16* woT  = (bf16*)(ws + 6 * MB);     // 2 MB  wo^T
    bf16* wkaT = (bf16*)(ws + 8 * MB);     // 2 MB  wka^T
    bf16* WqkT = (bf16*)(ws + 10 * MB);    // 2 MB  wk@wq^T  (rows 0..1023 of concat)
    bf16* wvoT = (bf16*)(ws + 12 * MB);    // 2 MB  (wv@wo)^T (rows 1024..2047, contiguous)
    bf16* xb   = (bf16*)(ws + 14 * MB);    // 8 MB  x bf16
    bf16* Qh   = (bf16*)(ws + 22 * MB);    // 8 MB  x@Wqk
    bf16* Vtp  = (bf16*)(ws + 30 * MB);    // 9 MB  [1024][4608] V'^T padded
    bf16* St   = (bf16*)(ws + 40 * MB);    // 5.25 MB [4096][640]
    bf16* fT   = (bf16*)(ws + 46 * MB);    // 8 MB  PV out = y@wo
    bf16* fL1  = (bf16*)(ws + 54 * MB);    // 8 MB  ln1 out
    bf16* fRel = (bf16*)(ws + 62 * MB);    // 8 MB  relu(.@wka+bka)

    PrepArgs pa;
    pa.x = x; pa.xb = xb; pa.Vtp = Vtp;
    pa.srcw[0] = wk;  pa.srcw[1] = wq;  pa.srcw[2] = wv;  pa.srcw[3] = wo;  pa.srcw[4] = wka;
    pa.dstw[0] = wkB; pa.dstw[1] = wqB; pa.dstw[2] = wvB; pa.dstw[3] = woT; pa.dstw[4] = wkaT;
    prep_kernel<<<3840, 256, 0, stream>>>(pa);

    // z=0: WqkT = wk@wq^T ; z=1: wvoT = wo^T@wv^T  (128x64 tiles, one launch)
    MiniPtrs mp;
    mp.A[0] = wkB; mp.Bt[0] = wqB; mp.C[0] = WqkT;
    mp.A[1] = woT; mp.Bt[1] = wvB; mp.C[1] = wvoT;
    gemm_mini<<<dim3(16, 8, 2), 256, 0, stream>>>(mp);

    // [Qh | V'] = xb @ [WqkT; wvoT]^T ; Qh half -> Qh buffer, V' half -> Vtp transposed
    gemm_kqv<<<dim3(16, 32), 256, 0, stream>>>(xb, WqkT, Qh, Vtp);

    score_gemm<<<dim3(WIN / 64, NROW / 128), 256, 0, stream>>>(Qh, xb, St);
    softmax_band<<<NROW / 4, 256, 0, stream>>>(St);
    // t = y@wo = St @ V'(band) : K=640, 128x128 tiles, per-j-tile Vtp column offset
    gemm_bt<128, 128><<<dim3(8, 32), 256, 0, stream>>>(
        St, WIN, Vtp, VTPW, fT, DIM, WIN, 1.f, nullptr, 0, 1);

    ln_kernel<<<NROW, 256, 0, stream>>>(fT, xb, g_y, b_y, fL1);
    gemm_bt<128, 128><<<dim3(8, 32), 256, 0, stream>>>(
        fL1, DIM, wkaT, DIM, fRel, DIM, DIM, 1.f, bka, 1, 0);
    lnfinal_kernel<<<NROW, 256, 0, stream>>>(fRel, g_ka, b_ka, wkd, bkd, out);
}

// Round 13
// 119.037 us; speedup vs baseline: 1.0833x; 1.0833x over previous
//
#include <hip/hip_runtime.h>
#include <hip/hip_bf16.h>
#include <math.h>

typedef __hip_bfloat16 bf16;
typedef __attribute__((ext_vector_type(8))) short bf16x8;   // MFMA A/B frag (8 bf16)
typedef __attribute__((ext_vector_type(4))) float f32x4;    // MFMA C/D frag

#define NROW 4096
#define DIM  1024
#define APP  256
#define WIN  640          // band window per 128-row j-tile: 128 + 2*APP
#define VTPW 4608         // padded Vt width: 256 | 4096 | 256

__device__ __forceinline__ unsigned short f2bu(float f) {
    bf16 h = __float2bfloat16(f);
    return *reinterpret_cast<unsigned short*>(&h);
}
__device__ __forceinline__ float bu2f(unsigned short u) {
    bf16 h; *reinterpret_cast<unsigned short*>(&h) = u;
    return __bfloat162float(h);
}
__device__ __forceinline__ unsigned pk2(float a, float b) {
    return (unsigned)f2bu(a) | ((unsigned)f2bu(b) << 16);
}
__device__ __forceinline__ void gload_lds16(const void* g, void* l) {
    __builtin_amdgcn_global_load_lds(
        (const __attribute__((address_space(1))) unsigned int*)g,
        (__attribute__((address_space(3))) unsigned int*)l, 16, 0, 0);
}

// ================= fused prep: cast x | cast/transpose 5 weights | zero Vtp pads =================
struct PrepArgs { const float* x; bf16* xb; const float* srcw[5]; bf16* dstw[5]; bf16* Vtp; };
__global__ __launch_bounds__(256) void prep_kernel(PrepArgs p) {
    __shared__ float T[64][65];
    const int bid = blockIdx.x, t = threadIdx.x;
    if (bid < 2048) {
        size_t base = ((size_t)bid * 256 + t) * 8;
        float4 v0 = *(const float4*)(p.x + base);
        float4 v1 = *(const float4*)(p.x + base + 4);
        uint4 o;
        o.x = pk2(v0.x, v0.y); o.y = pk2(v0.z, v0.w);
        o.z = pk2(v1.x, v1.y); o.w = pk2(v1.z, v1.w);
        *(uint4*)(p.xb + base) = o;
        return;
    }
    if (bid < 3328) {
        int r = bid - 2048;
        const int z = r >> 8; r &= 255;
        const int r0 = (r & 15) * 64, c0 = (r >> 4) * 64;
        const float* in = p.srcw[z];
        bf16* out = p.dstw[z];
        if (z < 3) {
            #pragma unroll
            for (int c = 0; c < 4; ++c) {
                int row = (t >> 4) + c * 16, col = (t & 15) * 4;
                float4 v = *(const float4*)(in + (size_t)(r0 + row) * 1024 + c0 + col);
                uint2 o; o.x = pk2(v.x, v.y); o.y = pk2(v.z, v.w);
                *(uint2*)(out + (size_t)(r0 + row) * 1024 + c0 + col) = o;
            }
            return;
        }
        #pragma unroll
        for (int c = 0; c < 4; ++c) {
            int row = (t >> 4) + c * 16, col = (t & 15) * 4;
            float4 v = *(const float4*)(in + (size_t)(r0 + row) * 1024 + c0 + col);
            T[row][col] = v.x; T[row][col + 1] = v.y; T[row][col + 2] = v.z; T[row][col + 3] = v.w;
        }
        __syncthreads();
        #pragma unroll
        for (int c = 0; c < 4; ++c) {
            int orow = (t >> 4) + c * 16, ocol = (t & 15) * 4;
            uint2 o;
            o.x = pk2(T[ocol][orow], T[ocol + 1][orow]);
            o.y = pk2(T[ocol + 2][orow], T[ocol + 3][orow]);
            *(uint2*)(out + (size_t)(c0 + orow) * 1024 + r0 + ocol) = o;
        }
        return;
    }
    {
        int idx = (bid - 3328) * 256 + t;
        int row = idx >> 7;
        int c4  = idx & 127;
        int col = (c4 < 64) ? (c4 * 4) : (4352 + (c4 - 64) * 4);
        *(uint2*)(p.Vtp + (size_t)row * VTPW + col) = (uint2){0u, 0u};
    }
}

// ================= bf16 MFMA GEMM: C[M,N] = act(alpha*A@Bt^T + bias) =================
// A row-major [M,K] stride lda; Bt row-major [N,K] stride ldb; C stride ldc.
// pv!=0: Bt base += (m0>>7)*128 (banded PV: per-128-j-tile column offset into Vtp).
template <int BM, int BN>
__global__ __launch_bounds__(256) void gemm_bt(
    const bf16* __restrict__ A, int lda, const bf16* __restrict__ Bt, int ldb,
    bf16* __restrict__ C, int ldc, int K,
    float alpha, const float* __restrict__ bias, int relu, int pv)
{
    constexpr int WM = BM / 2, WN = BN / 2, AI = WM / 16, BJ = WN / 16;
    __shared__ bf16 As[BM * 64];
    __shared__ bf16 Bs[BN * 64];
    const int t = threadIdx.x, l = t & 63, w = t >> 6;
    const int wr = w >> 1, wc = w & 1;
    const int jl = l & 15, g = l >> 4;
    const int m0 = blockIdx.y * BM, n0 = blockIdx.x * BN;
    const bf16* Btb = pv ? (Bt + (size_t)(m0 >> 7) * 128) : Bt;

    f32x4 acc[AI][BJ];
    #pragma unroll
    for (int i = 0; i < AI; ++i)
        #pragma unroll
        for (int j = 0; j < BJ; ++j) acc[i][j] = (f32x4){0.f, 0.f, 0.f, 0.f};

    for (int kk = 0; kk < K; kk += 64) {
        __syncthreads();
        #pragma unroll
        for (int c = 0; c < BM / 32; ++c) {
            int q = t + c * 256;
            int row = q >> 3;
            int kel = ((q & 7) ^ (row & 7)) << 3;
            gload_lds16(A + (size_t)(m0 + row) * lda + kk + kel,
                        (char*)As + (c * 256 + w * 64) * 16);
        }
        #pragma unroll
        for (int c = 0; c < BN / 32; ++c) {
            int q = t + c * 256;
            int row = q >> 3;
            int kel = ((q & 7) ^ (row & 7)) << 3;
            gload_lds16(Btb + (size_t)(n0 + row) * ldb + kk + kel,
                        (char*)Bs + (c * 256 + w * 64) * 16);
        }
        __syncthreads();
        #pragma unroll
        for (int ks = 0; ks < 2; ++ks) {
            bf16x8 af[AI], bfr[BJ];
            #pragma unroll
            for (int i = 0; i < AI; ++i) {
                int ra = wr * WM + i * 16 + jl;
                af[i] = *(const bf16x8*)((char*)As + ra * 128 + ((ks * 64 + g * 16) ^ ((ra & 7) << 4)));
            }
            #pragma unroll
            for (int j = 0; j < BJ; ++j) {
                int rb = wc * WN + j * 16 + jl;
                bfr[j] = *(const bf16x8*)((char*)Bs + rb * 128 + ((ks * 64 + g * 16) ^ ((rb & 7) << 4)));
            }
            #pragma unroll
            for (int i = 0; i < AI; ++i)
                #pragma unroll
                for (int j = 0; j < BJ; ++j)
                    acc[i][j] = __builtin_amdgcn_mfma_f32_16x16x32_bf16(af[i], bfr[j], acc[i][j], 0, 0, 0);
        }
    }

    const int g4 = g * 4;
    #pragma unroll
    for (int j = 0; j < BJ; ++j) {
        int col = n0 + wc * WN + j * 16 + jl;
        float bv = bias ? bias[col] : 0.f;
        #pragma unroll
        for (int i = 0; i < AI; ++i) {
            int rowb = m0 + wr * WM + i * 16 + g4;
            #pragma unroll
            for (int r = 0; r < 4; ++r) {
                float vv = alpha * acc[i][j][r] + bv;
                if (relu) vv = fmaxf(vv, 0.f);
                C[(size_t)(rowb + r) * ldc + col] = __float2bfloat16(vv);
            }
        }
    }
}

// ================= combined QV GEMM with split epilogue =================
// O = xb @ Wcat^T, Wcat = [WqkT; wvoT] (2048 rows). Columns 0..1023 -> Qh normally;
// columns 1024..2047 -> written TRANSPOSED into Vtp[d][256+j] (V'^T, padded).
__global__ __launch_bounds__(256) void gemm_kqv(
    const bf16* __restrict__ xb, const bf16* __restrict__ Wcat,
    bf16* __restrict__ Qh, bf16* __restrict__ Vtp)
{
    constexpr int BM = 128, BN = 128, WM = 64, WN = 64, AI = 4, BJ = 4;
    __shared__ bf16 As[BM * 64];
    __shared__ bf16 Bs[BN * 64];
    const int t = threadIdx.x, l = t & 63, w = t >> 6;
    const int wr = w >> 1, wc = w & 1;
    const int jl = l & 15, g = l >> 4;
    const int m0 = blockIdx.y * BM, n0 = blockIdx.x * BN;

    f32x4 acc[AI][BJ];
    #pragma unroll
    for (int i = 0; i < AI; ++i)
        #pragma unroll
        for (int j = 0; j < BJ; ++j) acc[i][j] = (f32x4){0.f, 0.f, 0.f, 0.f};

    for (int kk = 0; kk < DIM; kk += 64) {
        __syncthreads();
        #pragma unroll
        for (int c = 0; c < 4; ++c) {
            int q = t + c * 256;
            int row = q >> 3;
            int kel = ((q & 7) ^ (row & 7)) << 3;
            gload_lds16(xb + (size_t)(m0 + row) * DIM + kk + kel,
                        (char*)As + (c * 256 + w * 64) * 16);
            gload_lds16(Wcat + (size_t)(n0 + row) * DIM + kk + kel,
                        (char*)Bs + (c * 256 + w * 64) * 16);
        }
        __syncthreads();
        #pragma unroll
        for (int ks = 0; ks < 2; ++ks) {
            bf16x8 af[AI], bfr[BJ];
            #pragma unroll
            for (int i = 0; i < AI; ++i) {
                int ra = wr * WM + i * 16 + jl;
                af[i] = *(const bf16x8*)((char*)As + ra * 128 + ((ks * 64 + g * 16) ^ ((ra & 7) << 4)));
            }
            #pragma unroll
            for (int j = 0; j < BJ; ++j) {
                int rb = wc * WN + j * 16 + jl;
                bfr[j] = *(const bf16x8*)((char*)Bs + rb * 128 + ((ks * 64 + g * 16) ^ ((rb & 7) << 4)));
            }
            #pragma unroll
            for (int i = 0; i < AI; ++i)
                #pragma unroll
                for (int j = 0; j < BJ; ++j)
                    acc[i][j] = __builtin_amdgcn_mfma_f32_16x16x32_bf16(af[i], bfr[j], acc[i][j], 0, 0, 0);
        }
    }

    const int g4 = g * 4;
    if (n0 < 1024) {
        // Qh half: standard row-major store
        #pragma unroll
        for (int j = 0; j < BJ; ++j) {
            int col = n0 + wc * WN + j * 16 + jl;
            #pragma unroll
            for (int i = 0; i < AI; ++i) {
                int rowb = m0 + wr * WM + i * 16 + g4;
                #pragma unroll
                for (int r = 0; r < 4; ++r)
                    Qh[(size_t)(rowb + r) * DIM + col] = __float2bfloat16(acc[i][j][r]);
            }
        }
    } else {
        // V' half: acc[i][j][r] = V'[rowb+r][d], d = col-1024 -> Vtp[d][256+rowb+r]
        #pragma unroll
        for (int j = 0; j < BJ; ++j) {
            int d = n0 - 1024 + wc * WN + j * 16 + jl;
            #pragma unroll
            for (int i = 0; i < AI; ++i) {
                int rowb = m0 + wr * WM + i * 16 + g4;
                uint2 o;
                o.x = pk2(acc[i][j][0], acc[i][j][1]);
                o.y = pk2(acc[i][j][2], acc[i][j][3]);
                *(uint2*)(Vtp + (size_t)d * VTPW + 256 + rowb) = o;
            }
        }
    }
}

// ================= two 1024^3 mini GEMMs, 128x64 tiles (z=0: WqkT=wk@wq^T, z=1: wvoT=wo^T@wv^T) =================
struct MiniPtrs { const bf16* A[2]; const bf16* Bt[2]; bf16* C[2]; };
__global__ __launch_bounds__(256) void gemm_mini(MiniPtrs p) {
    constexpr int BM = 128, BN = 64, WM = 64, WN = 32, AI = 4, BJ = 2;
    __shared__ bf16 As[BM * 64];
    __shared__ bf16 Bs[BN * 64];
    const bf16* A  = p.A[blockIdx.z];
    const bf16* Bt = p.Bt[blockIdx.z];
    bf16* C        = p.C[blockIdx.z];
    const int t = threadIdx.x, l = t & 63, w = t >> 6;
    const int wr = w >> 1, wc = w & 1;
    const int jl = l & 15, g = l >> 4;
    const int m0 = blockIdx.y * BM, n0 = blockIdx.x * BN;

    f32x4 acc[AI][BJ];
    #pragma unroll
    for (int i = 0; i < AI; ++i)
        #pragma unroll
        for (int j = 0; j < BJ; ++j) acc[i][j] = (f32x4){0.f, 0.f, 0.f, 0.f};

    for (int kk = 0; kk < DIM; kk += 64) {
        __syncthreads();
        #pragma unroll
        for (int c = 0; c < BM / 32; ++c) {
            int q = t + c * 256;
            int row = q >> 3;
            int kel = ((q & 7) ^ (row & 7)) << 3;
            gload_lds16(A + (size_t)(m0 + row) * DIM + kk + kel,
                        (char*)As + (c * 256 + w * 64) * 16);
        }
        #pragma unroll
        for (int c = 0; c < BN / 32; ++c) {
            int q = t + c * 256;
            int row = q >> 3;
            int kel = ((q & 7) ^ (row & 7)) << 3;
            gload_lds16(Bt + (size_t)(n0 + row) * DIM + kk + kel,
                        (char*)Bs + (c * 256 + w * 64) * 16);
        }
        __syncthreads();
        #pragma unroll
        for (int ks = 0; ks < 2; ++ks) {
            bf16x8 af[AI], bfr[BJ];
            #pragma unroll
            for (int i = 0; i < AI; ++i) {
                int ra = wr * WM + i * 16 + jl;
                af[i] = *(const bf16x8*)((char*)As + ra * 128 + ((ks * 64 + g * 16) ^ ((ra & 7) << 4)));
            }
            #pragma unroll
            for (int j = 0; j < BJ; ++j) {
                int rb = wc * WN + j * 16 + jl;
                bfr[j] = *(const bf16x8*)((char*)Bs + rb * 128 + ((ks * 64 + g * 16) ^ ((rb & 7) << 4)));
            }
            #pragma unroll
            for (int i = 0; i < AI; ++i)
                #pragma unroll
                for (int j = 0; j < BJ; ++j)
                    acc[i][j] = __builtin_amdgcn_mfma_f32_16x16x32_bf16(af[i], bfr[j], acc[i][j], 0, 0, 0);
        }
    }

    const int g4 = g * 4;
    #pragma unroll
    for (int j = 0; j < BJ; ++j) {
        int col = n0 + wc * WN + j * 16 + jl;
        #pragma unroll
        for (int i = 0; i < AI; ++i) {
            int rowb = m0 + wr * WM + i * 16 + g4;
            #pragma unroll
            for (int r = 0; r < 4; ++r)
                C[(size_t)(rowb + r) * DIM + col] = __float2bfloat16(acc[i][j][r]);
        }
    }
}

// ================= banded score GEMM: St[j][iw] = 0.06 * Qh[win0+iw] . x[j] =================
__global__ __launch_bounds__(256) void score_gemm(const bf16* __restrict__ Qh,
                                                  const bf16* __restrict__ xb,
                                                  bf16* __restrict__ St)
{
    constexpr int WM = 32, WN = 64, AI = 2, BJ = 4;
    __shared__ bf16 As[64 * 64];
    __shared__ bf16 Bs[128 * 64];
    const int t = threadIdx.x, l = t & 63, w = t >> 6;
    const int wr = w >> 1, wc = w & 1;
    const int jl = l & 15, g = l >> 4;
    const int tt = blockIdx.y;              // j-tile 0..31
    const int c0 = blockIdx.x * 64;         // iw chunk base
    const int win0 = tt * 128 - APP;        // window start
    const bf16* Kb = xb + (size_t)tt * 128 * DIM;

    f32x4 acc[AI][BJ];
    #pragma unroll
    for (int i = 0; i < AI; ++i)
        #pragma unroll
        for (int j = 0; j < BJ; ++j) acc[i][j] = (f32x4){0.f, 0.f, 0.f, 0.f};

    for (int kk = 0; kk < DIM; kk += 64) {
        __syncthreads();
        #pragma unroll
        for (int c = 0; c < 2; ++c) {
            int q = t + c * 256;
            int row = q >> 3;
            int kel = ((q & 7) ^ (row & 7)) << 3;
            int rg = win0 + c0 + row;
            rg = min(max(rg, 0), NROW - 1);
            gload_lds16(Qh + (size_t)rg * DIM + kk + kel,
                        (char*)As + (c * 256 + w * 64) * 16);
        }
        #pragma unroll
        for (int c = 0; c < 4; ++c) {
            int q = t + c * 256;
            int row = q >> 3;
            int kel = ((q & 7) ^ (row & 7)) << 3;
            gload_lds16(Kb + (size_t)row * DIM + kk + kel,
                        (char*)Bs + (c * 256 + w * 64) * 16);
        }
        __syncthreads();
        #pragma unroll
        for (int ks = 0; ks < 2; ++ks) {
            bf16x8 af[AI], bfr[BJ];
            #pragma unroll
            for (int i = 0; i < AI; ++i) {
                int ra = wr * WM + i * 16 + jl;
                af[i] = *(const bf16x8*)((char*)As + ra * 128 + ((ks * 64 + g * 16) ^ ((ra & 7) << 4)));
            }
            #pragma unroll
            for (int j = 0; j < BJ; ++j) {
                int rb = wc * WN + j * 16 + jl;
                bfr[j] = *(const bf16x8*)((char*)Bs + rb * 128 + ((ks * 64 + g * 16) ^ ((rb & 7) << 4)));
            }
            #pragma unroll
            for (int i = 0; i < AI; ++i)
                #pragma unroll
                for (int j = 0; j < BJ; ++j)
                    acc[i][j] = __builtin_amdgcn_mfma_f32_16x16x32_bf16(af[i], bfr[j], acc[i][j], 0, 0, 0);
        }
    }

    const int g4 = g * 4;
    #pragma unroll
    for (int j = 0; j < BJ; ++j) {
        int coll = wc * WN + j * 16 + jl;
        bf16* strow = St + (size_t)(tt * 128 + coll) * WIN;
        #pragma unroll
        for (int i = 0; i < AI; ++i) {
            int iwb = c0 + wr * WM + i * 16 + g4;
            #pragma unroll
            for (int r = 0; r < 4; ++r)
                strow[iwb + r] = __float2bfloat16(0.06f * acc[i][j][r]);
        }
    }
}

// ================= masked row softmax over the 640-wide band window =================
__global__ __launch_bounds__(256) void softmax_band(bf16* __restrict__ St)
{
    const int w = threadIdx.x >> 6, l = threadIdx.x & 63;
    const int j = blockIdx.x * 4 + w;
    const int tt = j >> 7, jt = j & 127;
    unsigned* row = (unsigned*)(St + (size_t)j * WIN);
    const int lo = max(jt, 256 - 128 * tt);
    const int hi = min(jt + 512, 4351 - 128 * tt);
    unsigned u[5]; float v[10];
    #pragma unroll
    for (int c = 0; c < 5; ++c) u[c] = row[l + 64 * c];
    float m = -3e38f;
    #pragma unroll
    for (int c = 0; c < 5; ++c) {
        int iw = 2 * (l + 64 * c);
        v[2 * c]     = (iw >= lo && iw <= hi)         ? bu2f((unsigned short)(u[c] & 0xffff)) : -3e38f;
        v[2 * c + 1] = (iw + 1 >= lo && iw + 1 <= hi) ? bu2f((unsigned short)(u[c] >> 16))    : -3e38f;
        m = fmaxf(m, fmaxf(v[2 * c], v[2 * c + 1]));
    }
    #pragma unroll
    for (int off = 32; off > 0; off >>= 1) m = fmaxf(m, __shfl_xor(m, off));
    float s = 0.f;
    #pragma unroll
    for (int c = 0; c < 10; ++c) {
        float e = (v[c] > -1e37f) ? __expf(v[c] - m) : 0.f;
        v[c] = e; s += e;
    }
    #pragma unroll
    for (int off = 32; off > 0; off >>= 1) s += __shfl_xor(s, off);
    const float inv = 1.f / s;
    #pragma unroll
    for (int c = 0; c < 5; ++c)
        row[l + 64 * c] = pk2(v[2 * c] * inv, v[2 * c + 1] * inv);
}

// ================= LayerNorm: O = LN(T + Xb) * g + b  (Xb bf16 residual, may be null) =================
__global__ __launch_bounds__(256) void ln_kernel(
    const bf16* __restrict__ T, const bf16* __restrict__ Xb,
    const float* __restrict__ g, const float* __restrict__ b, bf16* __restrict__ O)
{
    __shared__ float red1[4], red2[4];
    const int r = blockIdx.x, t = threadIdx.x, lane = t & 63, w = t >> 6;
    ushort4 tv = ((const ushort4*)(T + (size_t)r * DIM))[t];
    float v0 = bu2f(tv.x), v1 = bu2f(tv.y), v2 = bu2f(tv.z), v3 = bu2f(tv.w);
    if (Xb) {
        ushort4 xv = ((const ushort4*)(Xb + (size_t)r * DIM))[t];
        v0 += bu2f(xv.x); v1 += bu2f(xv.y); v2 += bu2f(xv.z); v3 += bu2f(xv.w);
    }
    float s = v0 + v1 + v2 + v3;
    #pragma unroll
    for (int off = 32; off > 0; off >>= 1) s += __shfl_xor(s, off);
    if (lane == 0) red1[w] = s;
    __syncthreads();
    float mu = (red1[0] + red1[1] + red1[2] + red1[3]) * (1.f / DIM);
    float d0 = v0 - mu, d1 = v1 - mu, d2 = v2 - mu, d3 = v3 - mu;
    float s2 = d0 * d0 + d1 * d1 + d2 * d2 + d3 * d3;
    #pragma unroll
    for (int off = 32; off > 0; off >>= 1) s2 += __shfl_xor(s2, off);
    if (lane == 0) red2[w] = s2;
    __syncthreads();
    float var = (red2[0] + red2[1] + red2[2] + red2[3]) * (1.f / DIM);
    float rstd = rsqrtf(var + 1e-3f);
    float4 gv = ((const float4*)g)[t];
    float4 bv = ((const float4*)b)[t];
    uint2 o;
    o.x = pk2(d0 * rstd * gv.x + bv.x, d1 * rstd * gv.y + bv.y);
    o.y = pk2(d2 * rstd * gv.z + bv.z, d3 * rstd * gv.w + bv.w);
    ((uint2*)(O + (size_t)r * DIM))[t] = o;
}

// ================= fused LN2 + final: out[r] = sigmoid(LN(T[r]).wkd + bkd) =================
__global__ __launch_bounds__(256) void lnfinal_kernel(
    const bf16* __restrict__ T, const float* __restrict__ g, const float* __restrict__ b,
    const float* __restrict__ wkd, const float* __restrict__ bkd, float* __restrict__ out)
{
    __shared__ float red1[4], red2[4], red3[4];
    const int r = blockIdx.x, t = threadIdx.x, lane = t & 63, w = t >> 6;
    ushort4 tv = ((const ushort4*)(T + (size_t)r * DIM))[t];
    float v0 = bu2f(tv.x), v1 = bu2f(tv.y), v2 = bu2f(tv.z), v3 = bu2f(tv.w);
    float s = v0 + v1 + v2 + v3;
    #pragma unroll
    for (int off = 32; off > 0; off >>= 1) s += __shfl_xor(s, off);
    if (lane == 0) red1[w] = s;
    __syncthreads();
    float mu = (red1[0] + red1[1] + red1[2] + red1[3]) * (1.f / DIM);
    float d0 = v0 - mu, d1 = v1 - mu, d2 = v2 - mu, d3 = v3 - mu;
    float s2 = d0 * d0 + d1 * d1 + d2 * d2 + d3 * d3;
    #pragma unroll
    for (int off = 32; off > 0; off >>= 1) s2 += __shfl_xor(s2, off);
    if (lane == 0) red2[w] = s2;
    __syncthreads();
    float var = (red2[0] + red2[1] + red2[2] + red2[3]) * (1.f / DIM);
    float rstd = rsqrtf(var + 1e-3f);
    float4 gv = ((const float4*)g)[t];
    float4 bv = ((const float4*)b)[t];
    float4 wv = ((const float4*)wkd)[t];
    float s3 = (d0 * rstd * gv.x + bv.x) * wv.x + (d1 * rstd * gv.y + bv.y) * wv.y
             + (d2 * rstd * gv.z + bv.z) * wv.z + (d3 * rstd * gv.w + bv.w) * wv.w;
    #pragma unroll
    for (int off = 32; off > 0; off >>= 1) s3 += __shfl_xor(s3, off);
    if (lane == 0) red3[w] = s3;
    __syncthreads();
    if (t == 0) {
        float tot = red3[0] + red3[1] + red3[2] + red3[3];
        out[r] = 1.f / (1.f + __expf(-(tot + bkd[0])));
    }
}

extern "C" void kernel_launch(void* const* d_in, const int* in_sizes, int n_in,
                              void* d_out, int out_size, void* d_ws, size_t ws_size,
                              hipStream_t stream) {
    const float* x    = (const float*)d_in[0];
    const float* wk   = (const float*)d_in[1];
    const float* wq   = (const float*)d_in[2];
    const float* wv   = (const float*)d_in[3];
    const float* wo   = (const float*)d_in[4];
    const float* wka  = (const float*)d_in[5];
    const float* bka  = (const float*)d_in[6];
    const float* wkd  = (const float*)d_in[7];
    const float* bkd  = (const float*)d_in[8];
    const float* g_y  = (const float*)d_in[9];
    const float* b_y  = (const float*)d_in[10];
    const float* g_ka = (const float*)d_in[11];
    const float* b_ka = (const float*)d_in[12];
    float* out = (float*)d_out;

    char* ws = (char*)d_ws;
    const size_t MB = 1u << 20;
    bf16* wkB  = (bf16*)(ws);              // 2 MB  wk (plain)
    bf16* wqB  = (bf16*)(ws + 2 * MB);     // 2 MB  wq (plain)
    bf16* wvB  = (bf16*)(ws + 4 * MB);     // 2 MB  wv (plain)
    bf16* woT  = (bf16*)(ws + 6 * MB);     // 2 MB  wo^T
    bf16* wkaT = (bf16*)(ws + 8 * MB);     // 2 MB  wka^T
    bf16* WqkT = (bf16*)(ws + 10 * MB);    // 2 MB  wk@wq^T  (rows 0..1023 of concat)
    bf16* wvoT = (bf16*)(ws + 12 * MB);    // 2 MB  (wv@wo)^T (rows 1024..2047, contiguous)
    bf16* xb   = (bf16*)(ws + 14 * MB);    // 8 MB  x bf16
    bf16* Qh   = (bf16*)(ws + 22 * MB);    // 8 MB  x@Wqk
    bf16* Vtp  = (bf16*)(ws + 30 * MB);    // 9 MB  [1024][4608] V'^T padded
    bf16* St   = (bf16*)(ws + 40 * MB);    // 5.25 MB [4096][640]
    bf16* fT   = (bf16*)(ws + 46 * MB);    // 8 MB  PV out = y@wo
    bf16* fL1  = (bf16*)(ws + 54 * MB);    // 8 MB  ln1 out
    bf16* fRel = (bf16*)(ws + 62 * MB);    // 8 MB  relu(.@wka+bka)

    PrepArgs pa;
    pa.x = x; pa.xb = xb; pa.Vtp = Vtp;
    pa.srcw[0] = wk;  pa.srcw[1] = wq;  pa.srcw[2] = wv;  pa.srcw[3] = wo;  pa.srcw[4] = wka;
    pa.dstw[0] = wkB; pa.dstw[1] = wqB; pa.dstw[2] = wvB; pa.dstw[3] = woT; pa.dstw[4] = wkaT;
    prep_kernel<<<3840, 256, 0, stream>>>(pa);

    // z=0: WqkT = wk@wq^T ; z=1: wvoT = wo^T@wv^T  (128x64 tiles, one launch)
    MiniPtrs mp;
    mp.A[0] = wkB; mp.Bt[0] = wqB; mp.C[0] = WqkT;
    mp.A[1] = woT; mp.Bt[1] = wvB; mp.C[1] = wvoT;
    gemm_mini<<<dim3(16, 8, 2), 256, 0, stream>>>(mp);

    // [Qh | V'] = xb @ [WqkT; wvoT]^T ; Qh half -> Qh buffer, V' half -> Vtp transposed
    gemm_kqv<<<dim3(16, 32), 256, 0, stream>>>(xb, WqkT, Qh, Vtp);

    score_gemm<<<dim3(WIN / 64, NROW / 128), 256, 0, stream>>>(Qh, xb, St);
    softmax_band<<<NROW / 4, 256, 0, stream>>>(St);
    // t = y@wo = St @ V'(band) : K=640, 64x128 tiles (512 blocks = 2/CU)
    gemm_bt<64, 128><<<dim3(8, 64), 256, 0, stream>>>(
        St, WIN, Vtp, VTPW, fT, DIM, WIN, 1.f, nullptr, 0, 1);

    ln_kernel<<<NROW, 256, 0, stream>>>(fT, xb, g_y, b_y, fL1);
    gemm_bt<128, 64><<<dim3(16, 32), 256, 0, stream>>>(
        fL1, DIM, wkaT, DIM, fRel, DIM, DIM, 1.f, bka, 1, 0);
    lnfinal_kernel<<<NROW, 256, 0, stream>>>(fRel, g_ka, b_ka, wkd, bkd, out);
}

// Round 14
// 118.416 us; speedup vs baseline: 1.0890x; 1.0052x over previous
//
#include <hip/hip_runtime.h>
#include <hip/hip_bf16.h>
#include <math.h>

typedef __hip_bfloat16 bf16;
typedef __attribute__((ext_vector_type(8))) short bf16x8;   // MFMA A/B frag (8 bf16)
typedef __attribute__((ext_vector_type(4))) float f32x4;    // MFMA C/D frag

#define NROW 4096
#define DIM  1024
#define APP  256
#define WIN  640          // band window per 128-row j-tile: 128 + 2*APP
#define VTPW 4608         // padded Vt width: 256 | 4096 | 256

__device__ __forceinline__ unsigned short f2bu(float f) {
    bf16 h = __float2bfloat16(f);
    return *reinterpret_cast<unsigned short*>(&h);
}
__device__ __forceinline__ float bu2f(unsigned short u) {
    bf16 h; *reinterpret_cast<unsigned short*>(&h) = u;
    return __bfloat162float(h);
}
__device__ __forceinline__ unsigned pk2(float a, float b) {
    return (unsigned)f2bu(a) | ((unsigned)f2bu(b) << 16);
}
__device__ __forceinline__ void gload_lds16(const void* g, void* l) {
    __builtin_amdgcn_global_load_lds(
        (const __attribute__((address_space(1))) unsigned int*)g,
        (__attribute__((address_space(3))) unsigned int*)l, 16, 0, 0);
}

// ================= fused prep: cast x | cast/transpose 5 weights | zero Vtp pads =================
struct PrepArgs { const float* x; bf16* xb; const float* srcw[5]; bf16* dstw[5]; bf16* Vtp; };
__global__ __launch_bounds__(256) void prep_kernel(PrepArgs p) {
    __shared__ float T[64][65];
    const int bid = blockIdx.x, t = threadIdx.x;
    if (bid < 2048) {
        size_t base = ((size_t)bid * 256 + t) * 8;
        float4 v0 = *(const float4*)(p.x + base);
        float4 v1 = *(const float4*)(p.x + base + 4);
        uint4 o;
        o.x = pk2(v0.x, v0.y); o.y = pk2(v0.z, v0.w);
        o.z = pk2(v1.x, v1.y); o.w = pk2(v1.z, v1.w);
        *(uint4*)(p.xb + base) = o;
        return;
    }
    if (bid < 3328) {
        int r = bid - 2048;
        const int z = r >> 8; r &= 255;
        const int r0 = (r & 15) * 64, c0 = (r >> 4) * 64;
        const float* in = p.srcw[z];
        bf16* out = p.dstw[z];
        if (z < 3) {
            #pragma unroll
            for (int c = 0; c < 4; ++c) {
                int row = (t >> 4) + c * 16, col = (t & 15) * 4;
                float4 v = *(const float4*)(in + (size_t)(r0 + row) * 1024 + c0 + col);
                uint2 o; o.x = pk2(v.x, v.y); o.y = pk2(v.z, v.w);
                *(uint2*)(out + (size_t)(r0 + row) * 1024 + c0 + col) = o;
            }
            return;
        }
        #pragma unroll
        for (int c = 0; c < 4; ++c) {
            int row = (t >> 4) + c * 16, col = (t & 15) * 4;
            float4 v = *(const float4*)(in + (size_t)(r0 + row) * 1024 + c0 + col);
            T[row][col] = v.x; T[row][col + 1] = v.y; T[row][col + 2] = v.z; T[row][col + 3] = v.w;
        }
        __syncthreads();
        #pragma unroll
        for (int c = 0; c < 4; ++c) {
            int orow = (t >> 4) + c * 16, ocol = (t & 15) * 4;
            uint2 o;
            o.x = pk2(T[ocol][orow], T[ocol + 1][orow]);
            o.y = pk2(T[ocol + 2][orow], T[ocol + 3][orow]);
            *(uint2*)(out + (size_t)(c0 + orow) * 1024 + r0 + ocol) = o;
        }
        return;
    }
    {
        int idx = (bid - 3328) * 256 + t;
        int row = idx >> 7;
        int c4  = idx & 127;
        int col = (c4 < 64) ? (c4 * 4) : (4352 + (c4 - 64) * 4);
        *(uint2*)(p.Vtp + (size_t)row * VTPW + col) = (uint2){0u, 0u};
    }
}

// ================= bf16 MFMA GEMM: C[M,N] = act(alpha*A@Bt^T + bias) =================
// A row-major [M,K] stride lda; Bt row-major [N,K] stride ldb; C stride ldc.
// pv!=0: banded PV — Bt base += (m0>>7)*128 and K-loop starts at ((m0>>6)&1)*64
// (the complementary BK=64 chunk is exactly masked-zero in St).
template <int BM, int BN>
__global__ __launch_bounds__(256) void gemm_bt(
    const bf16* __restrict__ A, int lda, const bf16* __restrict__ Bt, int ldb,
    bf16* __restrict__ C, int ldc, int K,
    float alpha, const float* __restrict__ bias, int relu, int pv)
{
    constexpr int WM = BM / 2, WN = BN / 2, AI = WM / 16, BJ = WN / 16;
    __shared__ bf16 As[BM * 64];
    __shared__ bf16 Bs[BN * 64];
    const int t = threadIdx.x, l = t & 63, w = t >> 6;
    const int wr = w >> 1, wc = w & 1;
    const int jl = l & 15, g = l >> 4;
    const int m0 = blockIdx.y * BM, n0 = blockIdx.x * BN;
    const bf16* Btb = pv ? (Bt + (size_t)(m0 >> 7) * 128) : Bt;
    const int kbeg = pv ? ((m0 >> 6) & 1) * 64 : 0;

    f32x4 acc[AI][BJ];
    #pragma unroll
    for (int i = 0; i < AI; ++i)
        #pragma unroll
        for (int j = 0; j < BJ; ++j) acc[i][j] = (f32x4){0.f, 0.f, 0.f, 0.f};

    for (int kk = kbeg; kk < kbeg + K; kk += 64) {
        __syncthreads();
        #pragma unroll
        for (int c = 0; c < BM / 32; ++c) {
            int q = t + c * 256;
            int row = q >> 3;
            int kel = ((q & 7) ^ (row & 7)) << 3;
            gload_lds16(A + (size_t)(m0 + row) * lda + kk + kel,
                        (char*)As + (c * 256 + w * 64) * 16);
        }
        #pragma unroll
        for (int c = 0; c < BN / 32; ++c) {
            int q = t + c * 256;
            int row = q >> 3;
            int kel = ((q & 7) ^ (row & 7)) << 3;
            gload_lds16(Btb + (size_t)(n0 + row) * ldb + kk + kel,
                        (char*)Bs + (c * 256 + w * 64) * 16);
        }
        __syncthreads();
        #pragma unroll
        for (int ks = 0; ks < 2; ++ks) {
            bf16x8 af[AI], bfr[BJ];
            #pragma unroll
            for (int i = 0; i < AI; ++i) {
                int ra = wr * WM + i * 16 + jl;
                af[i] = *(const bf16x8*)((char*)As + ra * 128 + ((ks * 64 + g * 16) ^ ((ra & 7) << 4)));
            }
            #pragma unroll
            for (int j = 0; j < BJ; ++j) {
                int rb = wc * WN + j * 16 + jl;
                bfr[j] = *(const bf16x8*)((char*)Bs + rb * 128 + ((ks * 64 + g * 16) ^ ((rb & 7) << 4)));
            }
            #pragma unroll
            for (int i = 0; i < AI; ++i)
                #pragma unroll
                for (int j = 0; j < BJ; ++j)
                    acc[i][j] = __builtin_amdgcn_mfma_f32_16x16x32_bf16(af[i], bfr[j], acc[i][j], 0, 0, 0);
        }
    }

    const int g4 = g * 4;
    #pragma unroll
    for (int j = 0; j < BJ; ++j) {
        int col = n0 + wc * WN + j * 16 + jl;
        float bv = bias ? bias[col] : 0.f;
        #pragma unroll
        for (int i = 0; i < AI; ++i) {
            int rowb = m0 + wr * WM + i * 16 + g4;
            #pragma unroll
            for (int r = 0; r < 4; ++r) {
                float vv = alpha * acc[i][j][r] + bv;
                if (relu) vv = fmaxf(vv, 0.f);
                C[(size_t)(rowb + r) * ldc + col] = __float2bfloat16(vv);
            }
        }
    }
}

// ================= combined QV GEMM with split epilogue =================
// O = xb @ Wcat^T, Wcat = [WqkT; wvoT] (2048 rows). Columns 0..1023 -> Qh normally;
// columns 1024..2047 -> written TRANSPOSED into Vtp[d][256+j] (V'^T, padded).
__global__ __launch_bounds__(256) void gemm_kqv(
    const bf16* __restrict__ xb, const bf16* __restrict__ Wcat,
    bf16* __restrict__ Qh, bf16* __restrict__ Vtp)
{
    constexpr int BM = 128, BN = 128, WM = 64, WN = 64, AI = 4, BJ = 4;
    __shared__ bf16 As[BM * 64];
    __shared__ bf16 Bs[BN * 64];
    const int t = threadIdx.x, l = t & 63, w = t >> 6;
    const int wr = w >> 1, wc = w & 1;
    const int jl = l & 15, g = l >> 4;
    const int m0 = blockIdx.y * BM, n0 = blockIdx.x * BN;

    f32x4 acc[AI][BJ];
    #pragma unroll
    for (int i = 0; i < AI; ++i)
        #pragma unroll
        for (int j = 0; j < BJ; ++j) acc[i][j] = (f32x4){0.f, 0.f, 0.f, 0.f};

    for (int kk = 0; kk < DIM; kk += 64) {
        __syncthreads();
        #pragma unroll
        for (int c = 0; c < 4; ++c) {
            int q = t + c * 256;
            int row = q >> 3;
            int kel = ((q & 7) ^ (row & 7)) << 3;
            gload_lds16(xb + (size_t)(m0 + row) * DIM + kk + kel,
                        (char*)As + (c * 256 + w * 64) * 16);
            gload_lds16(Wcat + (size_t)(n0 + row) * DIM + kk + kel,
                        (char*)Bs + (c * 256 + w * 64) * 16);
        }
        __syncthreads();
        #pragma unroll
        for (int ks = 0; ks < 2; ++ks) {
            bf16x8 af[AI], bfr[BJ];
            #pragma unroll
            for (int i = 0; i < AI; ++i) {
                int ra = wr * WM + i * 16 + jl;
                af[i] = *(const bf16x8*)((char*)As + ra * 128 + ((ks * 64 + g * 16) ^ ((ra & 7) << 4)));
            }
            #pragma unroll
            for (int j = 0; j < BJ; ++j) {
                int rb = wc * WN + j * 16 + jl;
                bfr[j] = *(const bf16x8*)((char*)Bs + rb * 128 + ((ks * 64 + g * 16) ^ ((rb & 7) << 4)));
            }
            #pragma unroll
            for (int i = 0; i < AI; ++i)
                #pragma unroll
                for (int j = 0; j < BJ; ++j)
                    acc[i][j] = __builtin_amdgcn_mfma_f32_16x16x32_bf16(af[i], bfr[j], acc[i][j], 0, 0, 0);
        }
    }

    const int g4 = g * 4;
    if (n0 < 1024) {
        // Qh half: standard row-major store
        #pragma unroll
        for (int j = 0; j < BJ; ++j) {
            int col = n0 + wc * WN + j * 16 + jl;
            #pragma unroll
            for (int i = 0; i < AI; ++i) {
                int rowb = m0 + wr * WM + i * 16 + g4;
                #pragma unroll
                for (int r = 0; r < 4; ++r)
                    Qh[(size_t)(rowb + r) * DIM + col] = __float2bfloat16(acc[i][j][r]);
            }
        }
    } else {
        // V' half: acc[i][j][r] = V'[rowb+r][d], d = col-1024 -> Vtp[d][256+rowb+r]
        #pragma unroll
        for (int j = 0; j < BJ; ++j) {
            int d = n0 - 1024 + wc * WN + j * 16 + jl;
            #pragma unroll
            for (int i = 0; i < AI; ++i) {
                int rowb = m0 + wr * WM + i * 16 + g4;
                uint2 o;
                o.x = pk2(acc[i][j][0], acc[i][j][1]);
                o.y = pk2(acc[i][j][2], acc[i][j][3]);
                *(uint2*)(Vtp + (size_t)d * VTPW + 256 + rowb) = o;
            }
        }
    }
}

// ================= two 1024^3 mini GEMMs, 128x64 tiles (z=0: WqkT=wk@wq^T, z=1: wvoT=wo^T@wv^T) =================
struct MiniPtrs { const bf16* A[2]; const bf16* Bt[2]; bf16* C[2]; };
__global__ __launch_bounds__(256) void gemm_mini(MiniPtrs p) {
    constexpr int BM = 128, BN = 64, WM = 64, WN = 32, AI = 4, BJ = 2;
    __shared__ bf16 As[BM * 64];
    __shared__ bf16 Bs[BN * 64];
    const bf16* A  = p.A[blockIdx.z];
    const bf16* Bt = p.Bt[blockIdx.z];
    bf16* C        = p.C[blockIdx.z];
    const int t = threadIdx.x, l = t & 63, w = t >> 6;
    const int wr = w >> 1, wc = w & 1;
    const int jl = l & 15, g = l >> 4;
    const int m0 = blockIdx.y * BM, n0 = blockIdx.x * BN;

    f32x4 acc[AI][BJ];
    #pragma unroll
    for (int i = 0; i < AI; ++i)
        #pragma unroll
        for (int j = 0; j < BJ; ++j) acc[i][j] = (f32x4){0.f, 0.f, 0.f, 0.f};

    for (int kk = 0; kk < DIM; kk += 64) {
        __syncthreads();
        #pragma unroll
        for (int c = 0; c < BM / 32; ++c) {
            int q = t + c * 256;
            int row = q >> 3;
            int kel = ((q & 7) ^ (row & 7)) << 3;
            gload_lds16(A + (size_t)(m0 + row) * DIM + kk + kel,
                        (char*)As + (c * 256 + w * 64) * 16);
        }
        #pragma unroll
        for (int c = 0; c < BN / 32; ++c) {
            int q = t + c * 256;
            int row = q >> 3;
            int kel = ((q & 7) ^ (row & 7)) << 3;
            gload_lds16(Bt + (size_t)(n0 + row) * DIM + kk + kel,
                        (char*)Bs + (c * 256 + w * 64) * 16);
        }
        __syncthreads();
        #pragma unroll
        for (int ks = 0; ks < 2; ++ks) {
            bf16x8 af[AI], bfr[BJ];
            #pragma unroll
            for (int i = 0; i < AI; ++i) {
                int ra = wr * WM + i * 16 + jl;
                af[i] = *(const bf16x8*)((char*)As + ra * 128 + ((ks * 64 + g * 16) ^ ((ra & 7) << 4)));
            }
            #pragma unroll
            for (int j = 0; j < BJ; ++j) {
                int rb = wc * WN + j * 16 + jl;
                bfr[j] = *(const bf16x8*)((char*)Bs + rb * 128 + ((ks * 64 + g * 16) ^ ((rb & 7) << 4)));
            }
            #pragma unroll
            for (int i = 0; i < AI; ++i)
                #pragma unroll
                for (int j = 0; j < BJ; ++j)
                    acc[i][j] = __builtin_amdgcn_mfma_f32_16x16x32_bf16(af[i], bfr[j], acc[i][j], 0, 0, 0);
        }
    }

    const int g4 = g * 4;
    #pragma unroll
    for (int j = 0; j < BJ; ++j) {
        int col = n0 + wc * WN + j * 16 + jl;
        #pragma unroll
        for (int i = 0; i < AI; ++i) {
            int rowb = m0 + wr * WM + i * 16 + g4;
            #pragma unroll
            for (int r = 0; r < 4; ++r)
                C[(size_t)(rowb + r) * DIM + col] = __float2bfloat16(acc[i][j][r]);
        }
    }
}

// ================= banded score GEMM: St[j][iw] = 0.06 * Qh[win0+iw] . x[j] =================
// Blocks whose whole tile is out-of-band early-exit (St there is rewritten by softmax anyway).
__global__ __launch_bounds__(256) void score_gemm(const bf16* __restrict__ Qh,
                                                  const bf16* __restrict__ xb,
                                                  bf16* __restrict__ St)
{
    constexpr int WM = 32, WN = 64, AI = 2, BJ = 4;
    __shared__ bf16 As[64 * 64];
    __shared__ bf16 Bs[128 * 64];
    const int t = threadIdx.x, l = t & 63, w = t >> 6;
    const int wr = w >> 1, wc = w & 1;
    const int jl = l & 15, g = l >> 4;
    const int tt = blockIdx.y;              // j-tile 0..31
    const int c0 = blockIdx.x * 64;         // iw chunk base
    const int win0 = tt * 128 - APP;        // window start
    // whole-tile mask check: valid iw range across the 128 j-rows of this tile
    const int lo_min = max(0, 256 - 128 * tt);
    const int hi_max = min(639, 4351 - 128 * tt);
    if (c0 + 64 <= lo_min || c0 > hi_max) return;
    const bf16* Kb = xb + (size_t)tt * 128 * DIM;

    f32x4 acc[AI][BJ];
    #pragma unroll
    for (int i = 0; i < AI; ++i)
        #pragma unroll
        for (int j = 0; j < BJ; ++j) acc[i][j] = (f32x4){0.f, 0.f, 0.f, 0.f};

    for (int kk = 0; kk < DIM; kk += 64) {
        __syncthreads();
        #pragma unroll
        for (int c = 0; c < 2; ++c) {
            int q = t + c * 256;
            int row = q >> 3;
            int kel = ((q & 7) ^ (row & 7)) << 3;
            int rg = win0 + c0 + row;
            rg = min(max(rg, 0), NROW - 1);
            gload_lds16(Qh + (size_t)rg * DIM + kk + kel,
                        (char*)As + (c * 256 + w * 64) * 16);
        }
        #pragma unroll
        for (int c = 0; c < 4; ++c) {
            int q = t + c * 256;
            int row = q >> 3;
            int kel = ((q & 7) ^ (row & 7)) << 3;
            gload_lds16(Kb + (size_t)row * DIM + kk + kel,
                        (char*)Bs + (c * 256 + w * 64) * 16);
        }
        __syncthreads();
        #pragma unroll
        for (int ks = 0; ks < 2; ++ks) {
            bf16x8 af[AI], bfr[BJ];
            #pragma unroll
            for (int i = 0; i < AI; ++i) {
                int ra = wr * WM + i * 16 + jl;
                af[i] = *(const bf16x8*)((char*)As + ra * 128 + ((ks * 64 + g * 16) ^ ((ra & 7) << 4)));
            }
            #pragma unroll
            for (int j = 0; j < BJ; ++j) {
                int rb = wc * WN + j * 16 + jl;
                bfr[j] = *(const bf16x8*)((char*)Bs + rb * 128 + ((ks * 64 + g * 16) ^ ((rb & 7) << 4)));
            }
            #pragma unroll
            for (int i = 0; i < AI; ++i)
                #pragma unroll
                for (int j = 0; j < BJ; ++j)
                    acc[i][j] = __builtin_amdgcn_mfma_f32_16x16x32_bf16(af[i], bfr[j], acc[i][j], 0, 0, 0);
        }
    }

    const int g4 = g * 4;
    #pragma unroll
    for (int j = 0; j < BJ; ++j) {
        int coll = wc * WN + j * 16 + jl;
        bf16* strow = St + (size_t)(tt * 128 + coll) * WIN;
        #pragma unroll
        for (int i = 0; i < AI; ++i) {
            int iwb = c0 + wr * WM + i * 16 + g4;
            #pragma unroll
            for (int r = 0; r < 4; ++r)
                strow[iwb + r] = __float2bfloat16(0.06f * acc[i][j][r]);
        }
    }
}

// ================= masked row softmax over the 640-wide band window =================
__global__ __launch_bounds__(256) void softmax_band(bf16* __restrict__ St)
{
    const int w = threadIdx.x >> 6, l = threadIdx.x & 63;
    const int j = blockIdx.x * 4 + w;
    const int tt = j >> 7, jt = j & 127;
    unsigned* row = (unsigned*)(St + (size_t)j * WIN);
    const int lo = max(jt, 256 - 128 * tt);
    const int hi = min(jt + 512, 4351 - 128 * tt);
    unsigned u[5]; float v[10];
    #pragma unroll
    for (int c = 0; c < 5; ++c) u[c] = row[l + 64 * c];
    float m = -3e38f;
    #pragma unroll
    for (int c = 0; c < 5; ++c) {
        int iw = 2 * (l + 64 * c);
        v[2 * c]     = (iw >= lo && iw <= hi)         ? bu2f((unsigned short)(u[c] & 0xffff)) : -3e38f;
        v[2 * c + 1] = (iw + 1 >= lo && iw + 1 <= hi) ? bu2f((unsigned short)(u[c] >> 16))    : -3e38f;
        m = fmaxf(m, fmaxf(v[2 * c], v[2 * c + 1]));
    }
    #pragma unroll
    for (int off = 32; off > 0; off >>= 1) m = fmaxf(m, __shfl_xor(m, off));
    float s = 0.f;
    #pragma unroll
    for (int c = 0; c < 10; ++c) {
        float e = (v[c] > -1e37f) ? __expf(v[c] - m) : 0.f;
        v[c] = e; s += e;
    }
    #pragma unroll
    for (int off = 32; off > 0; off >>= 1) s += __shfl_xor(s, off);
    const float inv = 1.f / s;
    #pragma unroll
    for (int c = 0; c < 5; ++c)
        row[l + 64 * c] = pk2(v[2 * c] * inv, v[2 * c + 1] * inv);
}

// ================= LayerNorm: O = LN(T + Xb) * g + b  (Xb bf16 residual, may be null) =================
__global__ __launch_bounds__(256) void ln_kernel(
    const bf16* __restrict__ T, const bf16* __restrict__ Xb,
    const float* __restrict__ g, const float* __restrict__ b, bf16* __restrict__ O)
{
    __shared__ float red1[4], red2[4];
    const int r = blockIdx.x, t = threadIdx.x, lane = t & 63, w = t >> 6;
    ushort4 tv = ((const ushort4*)(T + (size_t)r * DIM))[t];
    float v0 = bu2f(tv.x), v1 = bu2f(tv.y), v2 = bu2f(tv.z), v3 = bu2f(tv.w);
    if (Xb) {
        ushort4 xv = ((const ushort4*)(Xb + (size_t)r * DIM))[t];
        v0 += bu2f(xv.x); v1 += bu2f(xv.y); v2 += bu2f(xv.z); v3 += bu2f(xv.w);
    }
    float s = v0 + v1 + v2 + v3;
    #pragma unroll
    for (int off = 32; off > 0; off >>= 1) s += __shfl_xor(s, off);
    if (lane == 0) red1[w] = s;
    __syncthreads();
    float mu = (red1[0] + red1[1] + red1[2] + red1[3]) * (1.f / DIM);
    float d0 = v0 - mu, d1 = v1 - mu, d2 = v2 - mu, d3 = v3 - mu;
    float s2 = d0 * d0 + d1 * d1 + d2 * d2 + d3 * d3;
    #pragma unroll
    for (int off = 32; off > 0; off >>= 1) s2 += __shfl_xor(s2, off);
    if (lane == 0) red2[w] = s2;
    __syncthreads();
    float var = (red2[0] + red2[1] + red2[2] + red2[3]) * (1.f / DIM);
    float rstd = rsqrtf(var + 1e-3f);
    float4 gv = ((const float4*)g)[t];
    float4 bv = ((const float4*)b)[t];
    uint2 o;
    o.x = pk2(d0 * rstd * gv.x + bv.x, d1 * rstd * gv.y + bv.y);
    o.y = pk2(d2 * rstd * gv.z + bv.z, d3 * rstd * gv.w + bv.w);
    ((uint2*)(O + (size_t)r * DIM))[t] = o;
}

// ================= fused LN2 + final: out[r] = sigmoid(LN(T[r]).wkd + bkd) =================
__global__ __launch_bounds__(256) void lnfinal_kernel(
    const bf16* __restrict__ T, const float* __restrict__ g, const float* __restrict__ b,
    const float* __restrict__ wkd, const float* __restrict__ bkd, float* __restrict__ out)
{
    __shared__ float red1[4], red2[4], red3[4];
    const int r = blockIdx.x, t = threadIdx.x, lane = t & 63, w = t >> 6;
    ushort4 tv = ((const ushort4*)(T + (size_t)r * DIM))[t];
    float v0 = bu2f(tv.x), v1 = bu2f(tv.y), v2 = bu2f(tv.z), v3 = bu2f(tv.w);
    float s = v0 + v1 + v2 + v3;
    #pragma unroll
    for (int off = 32; off > 0; off >>= 1) s += __shfl_xor(s, off);
    if (lane == 0) red1[w] = s;
    __syncthreads();
    float mu = (red1[0] + red1[1] + red1[2] + red1[3]) * (1.f / DIM);
    float d0 = v0 - mu, d1 = v1 - mu, d2 = v2 - mu, d3 = v3 - mu;
    float s2 = d0 * d0 + d1 * d1 + d2 * d2 + d3 * d3;
    #pragma unroll
    for (int off = 32; off > 0; off >>= 1) s2 += __shfl_xor(s2, off);
    if (lane == 0) red2[w] = s2;
    __syncthreads();
    float var = (red2[0] + red2[1] + red2[2] + red2[3]) * (1.f / DIM);
    float rstd = rsqrtf(var + 1e-3f);
    float4 gv = ((const float4*)g)[t];
    float4 bv = ((const float4*)b)[t];
    float4 wv = ((const float4*)wkd)[t];
    float s3 = (d0 * rstd * gv.x + bv.x) * wv.x + (d1 * rstd * gv.y + bv.y) * wv.y
             + (d2 * rstd * gv.z + bv.z) * wv.z + (d3 * rstd * gv.w + bv.w) * wv.w;
    #pragma unroll
    for (int off = 32; off > 0; off >>= 1) s3 += __shfl_xor(s3, off);
    if (lane == 0) red3[w] = s3;
    __syncthreads();
    if (t == 0) {
        float tot = red3[0] + red3[1] + red3[2] + red3[3];
        out[r] = 1.f / (1.f + __expf(-(tot + bkd[0])));
    }
}

extern "C" void kernel_launch(void* const* d_in, const int* in_sizes, int n_in,
                              void* d_out, int out_size, void* d_ws, size_t ws_size,
                              hipStream_t stream) {
    const float* x    = (const float*)d_in[0];
    const float* wk   = (const float*)d_in[1];
    const float* wq   = (const float*)d_in[2];
    const float* wv   = (const float*)d_in[3];
    const float* wo   = (const float*)d_in[4];
    const float* wka  = (const float*)d_in[5];
    const float* bka  = (const float*)d_in[6];
    const float* wkd  = (const float*)d_in[7];
    const float* bkd  = (const float*)d_in[8];
    const float* g_y  = (const float*)d_in[9];
    const float* b_y  = (const float*)d_in[10];
    const float* g_ka = (const float*)d_in[11];
    const float* b_ka = (const float*)d_in[12];
    float* out = (float*)d_out;

    char* ws = (char*)d_ws;
    const size_t MB = 1u << 20;
    bf16* wkB  = (bf16*)(ws);              // 2 MB  wk (plain)
    bf16* wqB  = (bf16*)(ws + 2 * MB);     // 2 MB  wq (plain)
    bf16* wvB  = (bf16*)(ws + 4 * MB);     // 2 MB  wv (plain)
    bf16* woT  = (bf16*)(ws + 6 * MB);     // 2 MB  wo^T
    bf16* wkaT = (bf16*)(ws + 8 * MB);     // 2 MB  wka^T
    bf16* WqkT = (bf16*)(ws + 10 * MB);    // 2 MB  wk@wq^T  (rows 0..1023 of concat)
    bf16* wvoT = (bf16*)(ws + 12 * MB);    // 2 MB  (wv@wo)^T (rows 1024..2047, contiguous)
    bf16* xb   = (bf16*)(ws + 14 * MB);    // 8 MB  x bf16
    bf16* Qh   = (bf16*)(ws + 22 * MB);    // 8 MB  x@Wqk
    bf16* Vtp  = (bf16*)(ws + 30 * MB);    // 9 MB  [1024][4608] V'^T padded
    bf16* St   = (bf16*)(ws + 40 * MB);    // 5.25 MB [4096][640]
    bf16* fT   = (bf16*)(ws + 46 * MB);    // 8 MB  PV out = y@wo
    bf16* fL1  = (bf16*)(ws + 54 * MB);    // 8 MB  ln1 out
    bf16* fRel = (bf16*)(ws + 62 * MB);    // 8 MB  relu(.@wka+bka)

    PrepArgs pa;
    pa.x = x; pa.xb = xb; pa.Vtp = Vtp;
    pa.srcw[0] = wk;  pa.srcw[1] = wq;  pa.srcw[2] = wv;  pa.srcw[3] = wo;  pa.srcw[4] = wka;
    pa.dstw[0] = wkB; pa.dstw[1] = wqB; pa.dstw[2] = wvB; pa.dstw[3] = woT; pa.dstw[4] = wkaT;
    prep_kernel<<<3840, 256, 0, stream>>>(pa);

    // z=0: WqkT = wk@wq^T ; z=1: wvoT = wo^T@wv^T  (128x64 tiles, one launch)
    MiniPtrs mp;
    mp.A[0] = wkB; mp.Bt[0] = wqB; mp.C[0] = WqkT;
    mp.A[1] = woT; mp.Bt[1] = wvB; mp.C[1] = wvoT;
    gemm_mini<<<dim3(16, 8, 2), 256, 0, stream>>>(mp);

    // [Qh | V'] = xb @ [WqkT; wvoT]^T ; Qh half -> Qh buffer, V' half -> Vtp transposed
    gemm_kqv<<<dim3(16, 32), 256, 0, stream>>>(xb, WqkT, Qh, Vtp);

    score_gemm<<<dim3(WIN / 64, NROW / 128), 256, 0, stream>>>(Qh, xb, St);
    softmax_band<<<NROW / 4, 256, 0, stream>>>(St);
    // t = y@wo = St @ V'(band) : 9 K-chunks of the 640 window (one chunk exactly masked)
    gemm_bt<64, 128><<<dim3(8, 64), 256, 0, stream>>>(
        St, WIN, Vtp, VTPW, fT, DIM, 576, 1.f, nullptr, 0, 1);

    ln_kernel<<<NROW, 256, 0, stream>>>(fT, xb, g_y, b_y, fL1);
    gemm_bt<128, 64><<<dim3(16, 32), 256, 0, stream>>>(
        fL1, DIM, wkaT, DIM, fRel, DIM, DIM, 1.f, bka, 1, 0);
    lnfinal_kernel<<<NROW, 256, 0, stream>>>(fRel, g_ka, b_ka, wkd, bkd, out);
}

// Round 15
// 115.648 us; speedup vs baseline: 1.1151x; 1.0239x over previous
//
#include <hip/hip_runtime.h>
#include <hip/hip_bf16.h>
#include <math.h>

typedef __hip_bfloat16 bf16;
typedef __attribute__((ext_vector_type(8))) short bf16x8;   // MFMA A/B frag (8 bf16)
typedef __attribute__((ext_vector_type(4))) float f32x4;    // MFMA C/D frag

#define NROW 4096
#define DIM  1024
#define APP  256
#define WIN  640          // band window per 128-row j-tile: 128 + 2*APP
#define VTPW 4608         // padded Vt width: 256 | 4096 | 256

__device__ __forceinline__ unsigned short f2bu(float f) {
    bf16 h = __float2bfloat16(f);
    return *reinterpret_cast<unsigned short*>(&h);
}
__device__ __forceinline__ float bu2f(unsigned short u) {
    bf16 h; *reinterpret_cast<unsigned short*>(&h) = u;
    return __bfloat162float(h);
}
__device__ __forceinline__ unsigned pk2(float a, float b) {
    return (unsigned)f2bu(a) | ((unsigned)f2bu(b) << 16);
}
__device__ __forceinline__ void gload_lds16(const void* g, void* l) {
    __builtin_amdgcn_global_load_lds(
        (const __attribute__((address_space(1))) unsigned int*)g,
        (__attribute__((address_space(3))) unsigned int*)l, 16, 0, 0);
}

// ================= weight prep: cast/transpose 5 weights =================
// 1280 blocks: z = bid>>8; z<3 plain cast (wk,wq,wv); z>=3 transpose (wo,wka)
struct PrepArgs { const float* srcw[5]; bf16* dstw[5]; };
__global__ __launch_bounds__(256) void prep_kernel(PrepArgs p) {
    __shared__ float T[64][65];
    const int t = threadIdx.x;
    int r = blockIdx.x;
    const int z = r >> 8; r &= 255;
    const int r0 = (r & 15) * 64, c0 = (r >> 4) * 64;
    const float* in = p.srcw[z];
    bf16* out = p.dstw[z];
    if (z < 3) {
        #pragma unroll
        for (int c = 0; c < 4; ++c) {
            int row = (t >> 4) + c * 16, col = (t & 15) * 4;
            float4 v = *(const float4*)(in + (size_t)(r0 + row) * 1024 + c0 + col);
            uint2 o; o.x = pk2(v.x, v.y); o.y = pk2(v.z, v.w);
            *(uint2*)(out + (size_t)(r0 + row) * 1024 + c0 + col) = o;
        }
        return;
    }
    #pragma unroll
    for (int c = 0; c < 4; ++c) {
        int row = (t >> 4) + c * 16, col = (t & 15) * 4;
        float4 v = *(const float4*)(in + (size_t)(r0 + row) * 1024 + c0 + col);
        T[row][col] = v.x; T[row][col + 1] = v.y; T[row][col + 2] = v.z; T[row][col + 3] = v.w;
    }
    __syncthreads();
    #pragma unroll
    for (int c = 0; c < 4; ++c) {
        int orow = (t >> 4) + c * 16, ocol = (t & 15) * 4;
        uint2 o;
        o.x = pk2(T[ocol][orow], T[ocol + 1][orow]);
        o.y = pk2(T[ocol + 2][orow], T[ocol + 3][orow]);
        *(uint2*)(out + (size_t)(c0 + orow) * 1024 + r0 + ocol) = o;
    }
}

// ================= mini GEMMs + x-cast + Vtp-pad zero, one launch =================
// 1D grid 2816 blocks:
//   [0,256)     two 1024^3 mini GEMMs 128x64 tiles: z=bid>>7 (0: WqkT=wk@wq^T, 1: wvoT=wo^T@wv^T)
//   [256,2304)  cast x -> xb (8 floats/thread)
//   [2304,2816) zero pad strips of Vtp (cols 0..255 and 4352..4607)
// No intra-launch dependencies: GEMM reads prev-launch weights; cast/pads write xb/Vtp
// which nothing here reads. GEMM blocks dispatch first; memory-bound cast overlaps them.
struct MiniArgs {
    const bf16* A[2]; const bf16* Bt[2]; bf16* C[2];
    const float* x; bf16* xb; bf16* Vtp;
};
__global__ __launch_bounds__(256) void mini_plus(MiniArgs p) {
    constexpr int BM = 128, BN = 64, WM = 64, WN = 32, AI = 4, BJ = 2;
    __shared__ bf16 As[BM * 64];
    __shared__ bf16 Bs[BN * 64];
    const int bid = blockIdx.x, t = threadIdx.x;

    if (bid >= 256) {
        if (bid < 2304) {
            size_t base = ((size_t)(bid - 256) * 256 + t) * 8;
            float4 v0 = *(const float4*)(p.x + base);
            float4 v1 = *(const float4*)(p.x + base + 4);
            uint4 o;
            o.x = pk2(v0.x, v0.y); o.y = pk2(v0.z, v0.w);
            o.z = pk2(v1.x, v1.y); o.w = pk2(v1.z, v1.w);
            *(uint4*)(p.xb + base) = o;
        } else {
            int idx = (bid - 2304) * 256 + t;
            int row = idx >> 7;
            int c4  = idx & 127;
            int col = (c4 < 64) ? (c4 * 4) : (4352 + (c4 - 64) * 4);
            *(uint2*)(p.Vtp + (size_t)row * VTPW + col) = (uint2){0u, 0u};
        }
        return;
    }

    const int z = bid >> 7, r = bid & 127;
    const int bx = r & 15, by = r >> 4;
    const bf16* A  = p.A[z];
    const bf16* Bt = p.Bt[z];
    bf16* C        = p.C[z];
    const int l = t & 63, w = t >> 6;
    const int wr = w >> 1, wc = w & 1;
    const int jl = l & 15, g = l >> 4;
    const int m0 = by * BM, n0 = bx * BN;

    f32x4 acc[AI][BJ];
    #pragma unroll
    for (int i = 0; i < AI; ++i)
        #pragma unroll
        for (int j = 0; j < BJ; ++j) acc[i][j] = (f32x4){0.f, 0.f, 0.f, 0.f};

    for (int kk = 0; kk < DIM; kk += 64) {
        __syncthreads();
        #pragma unroll
        for (int c = 0; c < BM / 32; ++c) {
            int q = t + c * 256;
            int row = q >> 3;
            int kel = ((q & 7) ^ (row & 7)) << 3;
            gload_lds16(A + (size_t)(m0 + row) * DIM + kk + kel,
                        (char*)As + (c * 256 + w * 64) * 16);
        }
        #pragma unroll
        for (int c = 0; c < BN / 32; ++c) {
            int q = t + c * 256;
            int row = q >> 3;
            int kel = ((q & 7) ^ (row & 7)) << 3;
            gload_lds16(Bt + (size_t)(n0 + row) * DIM + kk + kel,
                        (char*)Bs + (c * 256 + w * 64) * 16);
        }
        __syncthreads();
        #pragma unroll
        for (int ks = 0; ks < 2; ++ks) {
            bf16x8 af[AI], bfr[BJ];
            #pragma unroll
            for (int i = 0; i < AI; ++i) {
                int ra = wr * WM + i * 16 + jl;
                af[i] = *(const bf16x8*)((char*)As + ra * 128 + ((ks * 64 + g * 16) ^ ((ra & 7) << 4)));
            }
            #pragma unroll
            for (int j = 0; j < BJ; ++j) {
                int rb = wc * WN + j * 16 + jl;
                bfr[j] = *(const bf16x8*)((char*)Bs + rb * 128 + ((ks * 64 + g * 16) ^ ((rb & 7) << 4)));
            }
            #pragma unroll
            for (int i = 0; i < AI; ++i)
                #pragma unroll
                for (int j = 0; j < BJ; ++j)
                    acc[i][j] = __builtin_amdgcn_mfma_f32_16x16x32_bf16(af[i], bfr[j], acc[i][j], 0, 0, 0);
        }
    }

    const int g4 = g * 4;
    #pragma unroll
    for (int j = 0; j < BJ; ++j) {
        int col = n0 + wc * WN + j * 16 + jl;
        #pragma unroll
        for (int i = 0; i < AI; ++i) {
            int rowb = m0 + wr * WM + i * 16 + g4;
            #pragma unroll
            for (int r2 = 0; r2 < 4; ++r2)
                C[(size_t)(rowb + r2) * DIM + col] = __float2bfloat16(acc[i][j][r2]);
        }
    }
}

// ================= bf16 MFMA GEMM: C[M,N] = act(alpha*A@Bt^T + bias) =================
// A row-major [M,K] stride lda; Bt row-major [N,K] stride ldb; C stride ldc.
// pv!=0: banded PV — Bt base += (m0>>7)*128 and K-loop starts at ((m0>>6)&1)*64
// (the complementary BK=64 chunk is exactly masked-zero in St).
template <int BM, int BN>
__global__ __launch_bounds__(256) void gemm_bt(
    const bf16* __restrict__ A, int lda, const bf16* __restrict__ Bt, int ldb,
    bf16* __restrict__ C, int ldc, int K,
    float alpha, const float* __restrict__ bias, int relu, int pv)
{
    constexpr int WM = BM / 2, WN = BN / 2, AI = WM / 16, BJ = WN / 16;
    __shared__ bf16 As[BM * 64];
    __shared__ bf16 Bs[BN * 64];
    const int t = threadIdx.x, l = t & 63, w = t >> 6;
    const int wr = w >> 1, wc = w & 1;
    const int jl = l & 15, g = l >> 4;
    const int m0 = blockIdx.y * BM, n0 = blockIdx.x * BN;
    const bf16* Btb = pv ? (Bt + (size_t)(m0 >> 7) * 128) : Bt;
    const int kbeg = pv ? ((m0 >> 6) & 1) * 64 : 0;

    f32x4 acc[AI][BJ];
    #pragma unroll
    for (int i = 0; i < AI; ++i)
        #pragma unroll
        for (int j = 0; j < BJ; ++j) acc[i][j] = (f32x4){0.f, 0.f, 0.f, 0.f};

    for (int kk = kbeg; kk < kbeg + K; kk += 64) {
        __syncthreads();
        #pragma unroll
        for (int c = 0; c < BM / 32; ++c) {
            int q = t + c * 256;
            int row = q >> 3;
            int kel = ((q & 7) ^ (row & 7)) << 3;
            gload_lds16(A + (size_t)(m0 + row) * lda + kk + kel,
                        (char*)As + (c * 256 + w * 64) * 16);
        }
        #pragma unroll
        for (int c = 0; c < BN / 32; ++c) {
            int q = t + c * 256;
            int row = q >> 3;
            int kel = ((q & 7) ^ (row & 7)) << 3;
            gload_lds16(Btb + (size_t)(n0 + row) * ldb + kk + kel,
                        (char*)Bs + (c * 256 + w * 64) * 16);
        }
        __syncthreads();
        #pragma unroll
        for (int ks = 0; ks < 2; ++ks) {
            bf16x8 af[AI], bfr[BJ];
            #pragma unroll
            for (int i = 0; i < AI; ++i) {
                int ra = wr * WM + i * 16 + jl;
                af[i] = *(const bf16x8*)((char*)As + ra * 128 + ((ks * 64 + g * 16) ^ ((ra & 7) << 4)));
            }
            #pragma unroll
            for (int j = 0; j < BJ; ++j) {
                int rb = wc * WN + j * 16 + jl;
                bfr[j] = *(const bf16x8*)((char*)Bs + rb * 128 + ((ks * 64 + g * 16) ^ ((rb & 7) << 4)));
            }
            #pragma unroll
            for (int i = 0; i < AI; ++i)
                #pragma unroll
                for (int j = 0; j < BJ; ++j)
                    acc[i][j] = __builtin_amdgcn_mfma_f32_16x16x32_bf16(af[i], bfr[j], acc[i][j], 0, 0, 0);
        }
    }

    const int g4 = g * 4;
    #pragma unroll
    for (int j = 0; j < BJ; ++j) {
        int col = n0 + wc * WN + j * 16 + jl;
        float bv = bias ? bias[col] : 0.f;
        #pragma unroll
        for (int i = 0; i < AI; ++i) {
            int rowb = m0 + wr * WM + i * 16 + g4;
            #pragma unroll
            for (int r = 0; r < 4; ++r) {
                float vv = alpha * acc[i][j][r] + bv;
                if (relu) vv = fmaxf(vv, 0.f);
                C[(size_t)(rowb + r) * ldc + col] = __float2bfloat16(vv);
            }
        }
    }
}

// ================= combined QV GEMM with split epilogue =================
// O = xb @ Wcat^T, Wcat = [WqkT; wvoT] (2048 rows). Columns 0..1023 -> Qh normally;
// columns 1024..2047 -> written TRANSPOSED into Vtp[d][256+j] (V'^T, padded).
__global__ __launch_bounds__(256) void gemm_kqv(
    const bf16* __restrict__ xb, const bf16* __restrict__ Wcat,
    bf16* __restrict__ Qh, bf16* __restrict__ Vtp)
{
    constexpr int BM = 128, BN = 128, WM = 64, WN = 64, AI = 4, BJ = 4;
    __shared__ bf16 As[BM * 64];
    __shared__ bf16 Bs[BN * 64];
    const int t = threadIdx.x, l = t & 63, w = t >> 6;
    const int wr = w >> 1, wc = w & 1;
    const int jl = l & 15, g = l >> 4;
    const int m0 = blockIdx.y * BM, n0 = blockIdx.x * BN;

    f32x4 acc[AI][BJ];
    #pragma unroll
    for (int i = 0; i < AI; ++i)
        #pragma unroll
        for (int j = 0; j < BJ; ++j) acc[i][j] = (f32x4){0.f, 0.f, 0.f, 0.f};

    for (int kk = 0; kk < DIM; kk += 64) {
        __syncthreads();
        #pragma unroll
        for (int c = 0; c < 4; ++c) {
            int q = t + c * 256;
            int row = q >> 3;
            int kel = ((q & 7) ^ (row & 7)) << 3;
            gload_lds16(xb + (size_t)(m0 + row) * DIM + kk + kel,
                        (char*)As + (c * 256 + w * 64) * 16);
            gload_lds16(Wcat + (size_t)(n0 + row) * DIM + kk + kel,
                        (char*)Bs + (c * 256 + w * 64) * 16);
        }
        __syncthreads();
        #pragma unroll
        for (int ks = 0; ks < 2; ++ks) {
            bf16x8 af[AI], bfr[BJ];
            #pragma unroll
            for (int i = 0; i < AI; ++i) {
                int ra = wr * WM + i * 16 + jl;
                af[i] = *(const bf16x8*)((char*)As + ra * 128 + ((ks * 64 + g * 16) ^ ((ra & 7) << 4)));
            }
            #pragma unroll
            for (int j = 0; j < BJ; ++j) {
                int rb = wc * WN + j * 16 + jl;
                bfr[j] = *(const bf16x8*)((char*)Bs + rb * 128 + ((ks * 64 + g * 16) ^ ((rb & 7) << 4)));
            }
            #pragma unroll
            for (int i = 0; i < AI; ++i)
                #pragma unroll
                for (int j = 0; j < BJ; ++j)
                    acc[i][j] = __builtin_amdgcn_mfma_f32_16x16x32_bf16(af[i], bfr[j], acc[i][j], 0, 0, 0);
        }
    }

    const int g4 = g * 4;
    if (n0 < 1024) {
        // Qh half: standard row-major store
        #pragma unroll
        for (int j = 0; j < BJ; ++j) {
            int col = n0 + wc * WN + j * 16 + jl;
            #pragma unroll
            for (int i = 0; i < AI; ++i) {
                int rowb = m0 + wr * WM + i * 16 + g4;
                #pragma unroll
                for (int r = 0; r < 4; ++r)
                    Qh[(size_t)(rowb + r) * DIM + col] = __float2bfloat16(acc[i][j][r]);
            }
        }
    } else {
        // V' half: acc[i][j][r] = V'[rowb+r][d], d = col-1024 -> Vtp[d][256+rowb+r]
        #pragma unroll
        for (int j = 0; j < BJ; ++j) {
            int d = n0 - 1024 + wc * WN + j * 16 + jl;
            #pragma unroll
            for (int i = 0; i < AI; ++i) {
                int rowb = m0 + wr * WM + i * 16 + g4;
                uint2 o;
                o.x = pk2(acc[i][j][0], acc[i][j][1]);
                o.y = pk2(acc[i][j][2], acc[i][j][3]);
                *(uint2*)(Vtp + (size_t)d * VTPW + 256 + rowb) = o;
            }
        }
    }
}

// ================= banded score GEMM: St[j][iw] = 0.06 * Qh[win0+iw] . x[j] =================
// Blocks whose whole tile is out-of-band early-exit (St there is rewritten by softmax anyway).
__global__ __launch_bounds__(256) void score_gemm(const bf16* __restrict__ Qh,
                                                  const bf16* __restrict__ xb,
                                                  bf16* __restrict__ St)
{
    constexpr int WM = 32, WN = 64, AI = 2, BJ = 4;
    __shared__ bf16 As[64 * 64];
    __shared__ bf16 Bs[128 * 64];
    const int t = threadIdx.x, l = t & 63, w = t >> 6;
    const int wr = w >> 1, wc = w & 1;
    const int jl = l & 15, g = l >> 4;
    const int tt = blockIdx.y;              // j-tile 0..31
    const int c0 = blockIdx.x * 64;         // iw chunk base
    const int win0 = tt * 128 - APP;        // window start
    const int lo_min = max(0, 256 - 128 * tt);
    const int hi_max = min(639, 4351 - 128 * tt);
    if (c0 + 64 <= lo_min || c0 > hi_max) return;
    const bf16* Kb = xb + (size_t)tt * 128 * DIM;

    f32x4 acc[AI][BJ];
    #pragma unroll
    for (int i = 0; i < AI; ++i)
        #pragma unroll
        for (int j = 0; j < BJ; ++j) acc[i][j] = (f32x4){0.f, 0.f, 0.f, 0.f};

    for (int kk = 0; kk < DIM; kk += 64) {
        __syncthreads();
        #pragma unroll
        for (int c = 0; c < 2; ++c) {
            int q = t + c * 256;
            int row = q >> 3;
            int kel = ((q & 7) ^ (row & 7)) << 3;
            int rg = win0 + c0 + row;
            rg = min(max(rg, 0), NROW - 1);
            gload_lds16(Qh + (size_t)rg * DIM + kk + kel,
                        (char*)As + (c * 256 + w * 64) * 16);
        }
        #pragma unroll
        for (int c = 0; c < 4; ++c) {
            int q = t + c * 256;
            int row = q >> 3;
            int kel = ((q & 7) ^ (row & 7)) << 3;
            gload_lds16(Kb + (size_t)row * DIM + kk + kel,
                        (char*)Bs + (c * 256 + w * 64) * 16);
        }
        __syncthreads();
        #pragma unroll
        for (int ks = 0; ks < 2; ++ks) {
            bf16x8 af[AI], bfr[BJ];
            #pragma unroll
            for (int i = 0; i < AI; ++i) {
                int ra = wr * WM + i * 16 + jl;
                af[i] = *(const bf16x8*)((char*)As + ra * 128 + ((ks * 64 + g * 16) ^ ((ra & 7) << 4)));
            }
            #pragma unroll
            for (int j = 0; j < BJ; ++j) {
                int rb = wc * WN + j * 16 + jl;
                bfr[j] = *(const bf16x8*)((char*)Bs + rb * 128 + ((ks * 64 + g * 16) ^ ((rb & 7) << 4)));
            }
            #pragma unroll
            for (int i = 0; i < AI; ++i)
                #pragma unroll
                for (int j = 0; j < BJ; ++j)
                    acc[i][j] = __builtin_amdgcn_mfma_f32_16x16x32_bf16(af[i], bfr[j], acc[i][j], 0, 0, 0);
        }
    }

    const int g4 = g * 4;
    #pragma unroll
    for (int j = 0; j < BJ; ++j) {
        int coll = wc * WN + j * 16 + jl;
        bf16* strow = St + (size_t)(tt * 128 + coll) * WIN;
        #pragma unroll
        for (int i = 0; i < AI; ++i) {
            int iwb = c0 + wr * WM + i * 16 + g4;
            #pragma unroll
            for (int r = 0; r < 4; ++r)
                strow[iwb + r] = __float2bfloat16(0.06f * acc[i][j][r]);
        }
    }
}

// ================= masked row softmax over the 640-wide band window =================
__global__ __launch_bounds__(256) void softmax_band(bf16* __restrict__ St)
{
    const int w = threadIdx.x >> 6, l = threadIdx.x & 63;
    const int j = blockIdx.x * 4 + w;
    const int tt = j >> 7, jt = j & 127;
    unsigned* row = (unsigned*)(St + (size_t)j * WIN);
    const int lo = max(jt, 256 - 128 * tt);
    const int hi = min(jt + 512, 4351 - 128 * tt);
    unsigned u[5]; float v[10];
    #pragma unroll
    for (int c = 0; c < 5; ++c) u[c] = row[l + 64 * c];
    float m = -3e38f;
    #pragma unroll
    for (int c = 0; c < 5; ++c) {
        int iw = 2 * (l + 64 * c);
        v[2 * c]     = (iw >= lo && iw <= hi)         ? bu2f((unsigned short)(u[c] & 0xffff)) : -3e38f;
        v[2 * c + 1] = (iw + 1 >= lo && iw + 1 <= hi) ? bu2f((unsigned short)(u[c] >> 16))    : -3e38f;
        m = fmaxf(m, fmaxf(v[2 * c], v[2 * c + 1]));
    }
    #pragma unroll
    for (int off = 32; off > 0; off >>= 1) m = fmaxf(m, __shfl_xor(m, off));
    float s = 0.f;
    #pragma unroll
    for (int c = 0; c < 10; ++c) {
        float e = (v[c] > -1e37f) ? __expf(v[c] - m) : 0.f;
        v[c] = e; s += e;
    }
    #pragma unroll
    for (int off = 32; off > 0; off >>= 1) s += __shfl_xor(s, off);
    const float inv = 1.f / s;
    #pragma unroll
    for (int c = 0; c < 5; ++c)
        row[l + 64 * c] = pk2(v[2 * c] * inv, v[2 * c + 1] * inv);
}

// ================= LayerNorm: O = LN(T + Xb) * g + b  (Xb bf16 residual, may be null) =================
__global__ __launch_bounds__(256) void ln_kernel(
    const bf16* __restrict__ T, const bf16* __restrict__ Xb,
    const float* __restrict__ g, const float* __restrict__ b, bf16* __restrict__ O)
{
    __shared__ float red1[4], red2[4];
    const int r = blockIdx.x, t = threadIdx.x, lane = t & 63, w = t >> 6;
    ushort4 tv = ((const ushort4*)(T + (size_t)r * DIM))[t];
    float v0 = bu2f(tv.x), v1 = bu2f(tv.y), v2 = bu2f(tv.z), v3 = bu2f(tv.w);
    if (Xb) {
        ushort4 xv = ((const ushort4*)(Xb + (size_t)r * DIM))[t];
        v0 += bu2f(xv.x); v1 += bu2f(xv.y); v2 += bu2f(xv.z); v3 += bu2f(xv.w);
    }
    float s = v0 + v1 + v2 + v3;
    #pragma unroll
    for (int off = 32; off > 0; off >>= 1) s += __shfl_xor(s, off);
    if (lane == 0) red1[w] = s;
    __syncthreads();
    float mu = (red1[0] + red1[1] + red1[2] + red1[3]) * (1.f / DIM);
    float d0 = v0 - mu, d1 = v1 - mu, d2 = v2 - mu, d3 = v3 - mu;
    float s2 = d0 * d0 + d1 * d1 + d2 * d2 + d3 * d3;
    #pragma unroll
    for (int off = 32; off > 0; off >>= 1) s2 += __shfl_xor(s2, off);
    if (lane == 0) red2[w] = s2;
    __syncthreads();
    float var = (red2[0] + red2[1] + red2[2] + red2[3]) * (1.f / DIM);
    float rstd = rsqrtf(var + 1e-3f);
    float4 gv = ((const float4*)g)[t];
    float4 bv = ((const float4*)b)[t];
    uint2 o;
    o.x = pk2(d0 * rstd * gv.x + bv.x, d1 * rstd * gv.y + bv.y);
    o.y = pk2(d2 * rstd * gv.z + bv.z, d3 * rstd * gv.w + bv.w);
    ((uint2*)(O + (size_t)r * DIM))[t] = o;
}

// ================= fused LN2 + final: out[r] = sigmoid(LN(T[r]).wkd + bkd) =================
__global__ __launch_bounds__(256) void lnfinal_kernel(
    const bf16* __restrict__ T, const float* __restrict__ g, const float* __restrict__ b,
    const float* __restrict__ wkd, const float* __restrict__ bkd, float* __restrict__ out)
{
    __shared__ float red1[4], red2[4], red3[4];
    const int r = blockIdx.x, t = threadIdx.x, lane = t & 63, w = t >> 6;
    ushort4 tv = ((const ushort4*)(T + (size_t)r * DIM))[t];
    float v0 = bu2f(tv.x), v1 = bu2f(tv.y), v2 = bu2f(tv.z), v3 = bu2f(tv.w);
    float s = v0 + v1 + v2 + v3;
    #pragma unroll
    for (int off = 32; off > 0; off >>= 1) s += __shfl_xor(s, off);
    if (lane == 0) red1[w] = s;
    __syncthreads();
    float mu = (red1[0] + red1[1] + red1[2] + red1[3]) * (1.f / DIM);
    float d0 = v0 - mu, d1 = v1 - mu, d2 = v2 - mu, d3 = v3 - mu;
    float s2 = d0 * d0 + d1 * d1 + d2 * d2 + d3 * d3;
    #pragma unroll
    for (int off = 32; off > 0; off >>= 1) s2 += __shfl_xor(s2, off);
    if (lane == 0) red2[w] = s2;
    __syncthreads();
    float var = (red2[0] + red2[1] + red2[2] + red2[3]) * (1.f / DIM);
    float rstd = rsqrtf(var + 1e-3f);
    float4 gv = ((const float4*)g)[t];
    float4 bv = ((const float4*)b)[t];
    float4 wv = ((const float4*)wkd)[t];
    float s3 = (d0 * rstd * gv.x + bv.x) * wv.x + (d1 * rstd * gv.y + bv.y) * wv.y
             + (d2 * rstd * gv.z + bv.z) * wv.z + (d3 * rstd * gv.w + bv.w) * wv.w;
    #pragma unroll
    for (int off = 32; off > 0; off >>= 1) s3 += __shfl_xor(s3, off);
    if (lane == 0) red3[w] = s3;
    __syncthreads();
    if (t == 0) {
        float tot = red3[0] + red3[1] + red3[2] + red3[3];
        out[r] = 1.f / (1.f + __expf(-(tot + bkd[0])));
    }
}

extern "C" void kernel_launch(void* const* d_in, const int* in_sizes, int n_in,
                              void* d_out, int out_size, void* d_ws, size_t ws_size,
                              hipStream_t stream) {
    const float* x    = (const float*)d_in[0];
    const float* wk   = (const float*)d_in[1];
    const float* wq   = (const float*)d_in[2];
    const float* wv   = (const float*)d_in[3];
    const float* wo   = (const float*)d_in[4];
    const float* wka  = (const float*)d_in[5];
    const float* bka  = (const float*)d_in[6];
    const float* wkd  = (const float*)d_in[7];
    const float* bkd  = (const float*)d_in[8];
    const float* g_y  = (const float*)d_in[9];
    const float* b_y  = (const float*)d_in[10];
    const float* g_ka = (const float*)d_in[11];
    const float* b_ka = (const float*)d_in[12];
    float* out = (float*)d_out;

    char* ws = (char*)d_ws;
    const size_t MB = 1u << 20;
    bf16* wkB  = (bf16*)(ws);              // 2 MB  wk (plain)
    bf16* wqB  = (bf16*)(ws + 2 * MB);     // 2 MB  wq (plain)
    bf16* wvB  = (bf16*)(ws + 4 * MB);     // 2 MB  wv (plain)
    bf16* woT  = (bf16*)(ws + 6 * MB);     // 2 MB  wo^T
    bf16* wkaT = (bf16*)(ws + 8 * MB);     // 2 MB  wka^T
    bf16* WqkT = (bf16*)(ws + 10 * MB);    // 2 MB  wk@wq^T  (rows 0..1023 of concat)
    bf16* wvoT = (bf16*)(ws + 12 * MB);    // 2 MB  (wv@wo)^T (rows 1024..2047, contiguous)
    bf16* xb   = (bf16*)(ws + 14 * MB);    // 8 MB  x bf16
    bf16* Qh   = (bf16*)(ws + 22 * MB);    // 8 MB  x@Wqk
    bf16* Vtp  = (bf16*)(ws + 30 * MB);    // 9 MB  [1024][4608] V'^T padded
    bf16* St   = (bf16*)(ws + 40 * MB);    // 5.25 MB [4096][640]
    bf16* fT   = (bf16*)(ws + 46 * MB);    // 8 MB  PV out = y@wo
    bf16* fL1  = (bf16*)(ws + 54 * MB);    // 8 MB  ln1 out
    bf16* fRel = (bf16*)(ws + 62 * MB);    // 8 MB  relu(.@wka+bka)

    PrepArgs pa;
    pa.srcw[0] = wk;  pa.srcw[1] = wq;  pa.srcw[2] = wv;  pa.srcw[3] = wo;  pa.srcw[4] = wka;
    pa.dstw[0] = wkB; pa.dstw[1] = wqB; pa.dstw[2] = wvB; pa.dstw[3] = woT; pa.dstw[4] = wkaT;
    prep_kernel<<<1280, 256, 0, stream>>>(pa);

    // mini GEMMs (z=0: WqkT = wk@wq^T ; z=1: wvoT = wo^T@wv^T) + x-cast + Vtp pads, one launch
    MiniArgs ma;
    ma.A[0] = wkB; ma.Bt[0] = wqB; ma.C[0] = WqkT;
    ma.A[1] = woT; ma.Bt[1] = wvB; ma.C[1] = wvoT;
    ma.x = x; ma.xb = xb; ma.Vtp = Vtp;
    mini_plus<<<2816, 256, 0, stream>>>(ma);

    // [Qh | V'] = xb @ [WqkT; wvoT]^T ; Qh half -> Qh buffer, V' half -> Vtp transposed
    gemm_kqv<<<dim3(16, 32), 256, 0, stream>>>(xb, WqkT, Qh, Vtp);

    score_gemm<<<dim3(WIN / 64, NROW / 128), 256, 0, stream>>>(Qh, xb, St);
    softmax_band<<<NROW / 4, 256, 0, stream>>>(St);
    // t = y@wo = St @ V'(band) : 9 K-chunks of the 640 window (one chunk exactly masked)
    gemm_bt<64, 128><<<dim3(8, 64), 256, 0, stream>>>(
        St, WIN, Vtp, VTPW, fT, DIM, 576, 1.f, nullptr, 0, 1);

    ln_kernel<<<NROW, 256, 0, stream>>>(fT, xb, g_y, b_y, fL1);
    gemm_bt<128, 64><<<dim3(16, 32), 256, 0, stream>>>(
        fL1, DIM, wkaT, DIM, fRel, DIM, DIM, 1.f, bka, 1, 0);
    lnfinal_kernel<<<NROW, 256, 0, stream>>>(fRel, g_ka, b_ka, wkd, bkd, out);
}